// Round 9
// baseline (488.192 us; speedup 1.0000x reference)
//
#include <hip/hip_runtime.h>
#include <cstdint>

typedef __attribute__((ext_vector_type(8))) short short8;
typedef __attribute__((ext_vector_type(4))) float f32x4;
typedef unsigned short u16t;

// ---------- helpers ----------
__device__ __forceinline__ u16t f2bf(float f) {
  uint32_t u = __float_as_uint(f);
  u += 0x7fffu + ((u >> 16) & 1u);   // RNE
  return (u16t)(u >> 16);
}

__device__ __forceinline__ uint32_t cvtpk(float lo, float hi) {
  uint32_t r;
  asm("v_cvt_pk_bf16_f32 %0, %1, %2" : "=v"(r) : "v"(lo), "v"(hi));
  return r;
}

__device__ __forceinline__ void gload_lds16(const void* g, void* l) {
  __builtin_amdgcn_global_load_lds(
      (const __attribute__((address_space(1))) void*)g,
      (__attribute__((address_space(3))) void*)l, 16, 0, 0);
}

__device__ __forceinline__ float gelu_exact(float v) {
  return 0.5f * v * (1.0f + erff(v * 0.70710678118f));
}

// ---------- f32 -> bf16 convert ----------
__global__ __launch_bounds__(256) void cvt_bf16_kernel(const float* __restrict__ in,
                                                       u16t* __restrict__ out, int n8) {
  int i = blockIdx.x * 256 + threadIdx.x;
  if (i >= n8) return;
  const float4* p = (const float4*)in + (size_t)i * 2;
  float4 a = p[0], b = p[1];
  union { short8 v; u16t e[8]; } r;
  r.e[0] = f2bf(a.x); r.e[1] = f2bf(a.y); r.e[2] = f2bf(a.z); r.e[3] = f2bf(a.w);
  r.e[4] = f2bf(b.x); r.e[5] = f2bf(b.y); r.e[6] = f2bf(b.z); r.e[7] = f2bf(b.w);
  *((short8*)out + i) = r.v;
}

// ---------- LayerNorm (row = 768 f32) -> bf16 ----------
__global__ __launch_bounds__(256) void ln_kernel(const float* __restrict__ x,
                                                 const float* __restrict__ g,
                                                 const float* __restrict__ b,
                                                 u16t* __restrict__ out) {
  int row = blockIdx.x, tid = threadIdx.x;
  int wave = tid >> 6, lane = tid & 63;
  const float* xr = x + (size_t)row * 768;
  float v0 = xr[tid], v1 = xr[tid + 256], v2 = xr[tid + 512];
  float s = v0 + v1 + v2;
  float q = v0 * v0 + v1 * v1 + v2 * v2;
#pragma unroll
  for (int m = 32; m >= 1; m >>= 1) {
    s += __shfl_xor(s, m, 64);
    q += __shfl_xor(q, m, 64);
  }
  __shared__ float red[8];
  if (lane == 0) { red[wave] = s; red[4 + wave] = q; }
  __syncthreads();
  s = red[0] + red[1] + red[2] + red[3];
  q = red[4] + red[5] + red[6] + red[7];
  float mu = s * (1.0f / 768.0f);
  float var = q * (1.0f / 768.0f) - mu * mu;
  float rs = rsqrtf(var + 1e-5f);
  u16t* orow = out + (size_t)row * 768;
  orow[tid]       = f2bf((v0 - mu) * rs * g[tid]       + b[tid]);
  orow[tid + 256] = f2bf((v1 - mu) * rs * g[tid + 256] + b[tid + 256]);
  orow[tid + 512] = f2bf((v2 - mu) * rs * g[tid + 512] + b[tid + 512]);
}

// ---------- GEMM 512thr: C[M,N] = A[M,K] @ W[N,K]^T, tile 128x256, BK=64 ----------
// Single-buffer 48KB LDS, serial 2-barrier loop (R5 structure — proven best),
// chunked bn-major XCD swizzle: each XCD owns contiguous bn columns -> W panels
// stay L2-resident. Packed swapped-operand epilogue.
template <int EPI>
__global__ __launch_bounds__(512, 3) void gemm5(const u16t* __restrict__ A,
                                                const u16t* __restrict__ W,
                                                void* __restrict__ Cout,
                                                const float* __restrict__ bias,
                                                const float* __restrict__ res,
                                                int N, int K, int nbm) {
  __shared__ __align__(16) u16t As[128 * 64];
  __shared__ __align__(16) u16t Bs[256 * 64];
  int tid = threadIdx.x;
  int wid = tid >> 6, lane = tid & 63;
  int wr = wid >> 2, wc = wid & 3;
  int q = lane & 15, g = lane >> 4;

  // chunked bn-major swizzle: XCD x owns tiles [x*total/8, (x+1)*total/8)
  int total = gridDim.x;
  int bid = blockIdx.x;
  int swz = (bid & 7) * (total >> 3) + (bid >> 3);
  int bm = (swz % nbm) * 128;
  int bn = (swz / nbm) * 256;

  f32x4 acc[4][4] = {};

  int lr = lane >> 3, lc = lane & 7;
  const u16t* Abase = A + (size_t)(bm + lr) * K + ((lc ^ lr) * 8);
  const u16t* Wbase = W + (size_t)(bn + lr) * K + ((lc ^ lr) * 8);

  int NT = K >> 6;
  for (int t = 0; t < NT; ++t) {
    int kt = t * 64;
    // stage: A 16 chunks, B 32 chunks; 6 per wave
#pragma unroll
    for (int i = 0; i < 2; i++) {
      int chunk = wid * 2 + i;
      gload_lds16(Abase + (size_t)(chunk * 8) * K + kt, (void*)(As + chunk * 512));
    }
#pragma unroll
    for (int i = 0; i < 4; i++) {
      int chunk = wid * 4 + i;
      gload_lds16(Wbase + (size_t)(chunk * 8) * K + kt, (void*)(Bs + chunk * 512));
    }
    __syncthreads();

    short8 af[4][2], bfr[4][2];
#pragma unroll
    for (int m = 0; m < 4; m++) {
      int row = wr * 64 + m * 16 + q;
#pragma unroll
      for (int s = 0; s < 2; s++)
        af[m][s] = *(const short8*)(As + row * 64 + (((s * 4 + g) ^ (row & 7)) * 8));
    }
#pragma unroll
    for (int n = 0; n < 4; n++) {
      int row = wc * 64 + n * 16 + q;
#pragma unroll
      for (int s = 0; s < 2; s++)
        bfr[n][s] = *(const short8*)(Bs + row * 64 + (((s * 4 + g) ^ (row & 7)) * 8));
    }
    __builtin_amdgcn_s_setprio(1);
#pragma unroll
    for (int m = 0; m < 4; m++)
#pragma unroll
      for (int n = 0; n < 4; n++) {
        acc[m][n] = __builtin_amdgcn_mfma_f32_16x16x32_bf16(bfr[n][0], af[m][0], acc[m][n], 0, 0, 0);
        acc[m][n] = __builtin_amdgcn_mfma_f32_16x16x32_bf16(bfr[n][1], af[m][1], acc[m][n], 0, 0, 0);
      }
    __builtin_amdgcn_s_setprio(0);
    __syncthreads();
  }

#pragma unroll
  for (int m = 0; m < 4; m++) {
    int r = bm + wr * 64 + m * 16 + q;
#pragma unroll
    for (int n = 0; n < 4; n++) {
      int c = bn + wc * 64 + n * 16 + g * 4;
      f32x4 v = acc[m][n];
      if constexpr (EPI == 0) {
        uint2 pk = make_uint2(cvtpk(v[0], v[1]), cvtpk(v[2], v[3]));
        *(uint2*)((u16t*)Cout + (size_t)r * N + c) = pk;
      } else if constexpr (EPI == 1) {
        const float4 bv = *(const float4*)(bias + c);
        const float4 rv = *(const float4*)(res + (size_t)r * N + c);
        float4 o;
        o.x = v[0] + bv.x + rv.x; o.y = v[1] + bv.y + rv.y;
        o.z = v[2] + bv.z + rv.z; o.w = v[3] + bv.w + rv.w;
        *(float4*)((float*)Cout + (size_t)r * N + c) = o;
      } else {
        const float4 bv = *(const float4*)(bias + c);
        uint2 pk = make_uint2(cvtpk(gelu_exact(v[0] + bv.x), gelu_exact(v[1] + bv.y)),
                              cvtpk(gelu_exact(v[2] + bv.z), gelu_exact(v[3] + bv.w)));
        *(uint2*)((u16t*)Cout + (size_t)r * N + c) = pk;
      }
    }
  }
}

// ---------- GEMM 256thr: tile 128x128, BK=64 (for N=768 shapes) ----------
template <int EPI>
__global__ __launch_bounds__(256, 4) void gemm4(const u16t* __restrict__ A,
                                                const u16t* __restrict__ W,
                                                void* __restrict__ Cout,
                                                const float* __restrict__ bias,
                                                const float* __restrict__ res,
                                                int N, int K, int nbm) {
  __shared__ __align__(16) u16t As[128 * 64];
  __shared__ __align__(16) u16t Bs[128 * 64];
  int tid = threadIdx.x;
  int wave = tid >> 6, lane = tid & 63;
  int wr = wave >> 1, wc = wave & 1;
  int q = lane & 15, g = lane >> 4;

  int total = gridDim.x;
  int bid = blockIdx.x;
  int swz = (bid & 7) * (total >> 3) + (bid >> 3);
  int bm = (swz % nbm) * 128;
  int bn = (swz / nbm) * 128;

  f32x4 acc[4][4] = {};

  int lr = lane >> 3, lc = lane & 7;
  const u16t* Abase = A + (size_t)(bm + lr) * K + ((lc ^ lr) * 8);
  const u16t* Wbase = W + (size_t)(bn + lr) * K + ((lc ^ lr) * 8);

  int NT = K >> 6;
  for (int t = 0; t < NT; ++t) {
    int kt = t * 64;
#pragma unroll
    for (int i = 0; i < 4; i++) {
      int chunk = wave * 4 + i;
      gload_lds16(Abase + (size_t)(chunk * 8) * K + kt, (void*)(As + chunk * 512));
      gload_lds16(Wbase + (size_t)(chunk * 8) * K + kt, (void*)(Bs + chunk * 512));
    }
    __syncthreads();

    short8 af[4][2], bfr[4][2];
#pragma unroll
    for (int m = 0; m < 4; m++) {
      int row = wr * 64 + m * 16 + q;
#pragma unroll
      for (int s = 0; s < 2; s++)
        af[m][s] = *(const short8*)(As + row * 64 + (((s * 4 + g) ^ (row & 7)) * 8));
    }
#pragma unroll
    for (int n = 0; n < 4; n++) {
      int row = wc * 64 + n * 16 + q;
#pragma unroll
      for (int s = 0; s < 2; s++)
        bfr[n][s] = *(const short8*)(Bs + row * 64 + (((s * 4 + g) ^ (row & 7)) * 8));
    }
    __builtin_amdgcn_s_setprio(1);
#pragma unroll
    for (int m = 0; m < 4; m++)
#pragma unroll
      for (int n = 0; n < 4; n++) {
        acc[m][n] = __builtin_amdgcn_mfma_f32_16x16x32_bf16(bfr[n][0], af[m][0], acc[m][n], 0, 0, 0);
        acc[m][n] = __builtin_amdgcn_mfma_f32_16x16x32_bf16(bfr[n][1], af[m][1], acc[m][n], 0, 0, 0);
      }
    __builtin_amdgcn_s_setprio(0);
    __syncthreads();
  }

#pragma unroll
  for (int m = 0; m < 4; m++) {
    int r = bm + wr * 64 + m * 16 + q;
#pragma unroll
    for (int n = 0; n < 4; n++) {
      int c = bn + wc * 64 + n * 16 + g * 4;
      f32x4 v = acc[m][n];
      if constexpr (EPI == 0) {
        uint2 pk = make_uint2(cvtpk(v[0], v[1]), cvtpk(v[2], v[3]));
        *(uint2*)((u16t*)Cout + (size_t)r * N + c) = pk;
      } else if constexpr (EPI == 1) {
        const float4 bv = *(const float4*)(bias + c);
        const float4 rv = *(const float4*)(res + (size_t)r * N + c);
        float4 o;
        o.x = v[0] + bv.x + rv.x; o.y = v[1] + bv.y + rv.y;
        o.z = v[2] + bv.z + rv.z; o.w = v[3] + bv.w + rv.w;
        *(float4*)((float*)Cout + (size_t)r * N + c) = o;
      } else {
        const float4 bv = *(const float4*)(bias + c);
        uint2 pk = make_uint2(cvtpk(gelu_exact(v[0] + bv.x), gelu_exact(v[1] + bv.y)),
                              cvtpk(gelu_exact(v[2] + bv.z), gelu_exact(v[3] + bv.w)));
        *(uint2*)((u16t*)Cout + (size_t)r * N + c) = pk;
      }
    }
  }
}

// ---------- V transpose: qkvb V-part -> vt[head][64][1024] ----------
__global__ __launch_bounds__(256) void vtrans_kernel(const u16t* __restrict__ qkv,
                                                     u16t* __restrict__ vt) {
  __shared__ u16t T[64][66];
  int h = blockIdx.x % 12, bb = blockIdx.x / 12, kt = blockIdx.y * 64;
  int t = threadIdx.x;
  int r = t >> 2, dc = t & 3;
  const u16t* src = qkv + (size_t)(bb * 1024 + kt + r) * 2304 + 1536 + h * 64 + dc * 16;
  union { uint4 u[2]; u16t e[16]; uint32_t w[8]; } buf;
  buf.u[0] = *(const uint4*)src;
  buf.u[1] = *(const uint4*)(src + 8);
#pragma unroll
  for (int j = 0; j < 8; j++)
    *(uint32_t*)&T[r][dc * 16 + 2 * j] = buf.w[j];
  __syncthreads();
  int d = t >> 2, kc = t & 3;
  union { uint4 u[2]; u16t e[16]; } o;
#pragma unroll
  for (int j = 0; j < 16; j++) o.e[j] = T[kc * 16 + j][d];
  u16t* dst = vt + ((size_t)blockIdx.x * 64 + d) * 1024 + kt + kc * 16;
  *(uint4*)dst = o.u[0];
  *(uint4*)(dst + 8) = o.u[1];
}

// ---------- flash attention: block-shared LDS staging + 2-phase pipeline ----------
__global__ __launch_bounds__(256, 3) void attn_kernel(const u16t* __restrict__ qkv,
                                                      const u16t* __restrict__ vt,
                                                      u16t* __restrict__ ctx) {
  __shared__ __align__(16) u16t Ks[2][64 * 64];
  __shared__ __align__(16) u16t Vs[2][64 * 64];
  __shared__ __align__(16) u16t Plds[4][32 * 72];
  int tid = threadIdx.x;
  int wave = tid >> 6, lane = tid & 63;
  int q = lane & 15, g = lane >> 4;

  int bid = blockIdx.x;
  int xcd = bid & 7, j = bid >> 3;
  int head = xcd + 8 * (j >> 3);
  int qt = (j & 7) * 128 + wave * 32;
  int b = head / 12, h = head % 12;

  const u16t* base = qkv + (size_t)b * 1024 * 2304 + h * 64;
  const u16t* kbase = base + 768;
  const u16t* vtb = vt + (size_t)head * 64 * 1024;

  short8 qf[2][2];
#pragma unroll
  for (int hf = 0; hf < 2; hf++)
#pragma unroll
    for (int hh = 0; hh < 2; hh++)
      qf[hf][hh] = *(const short8*)(base + (size_t)(qt + hf * 16 + q) * 2304 + hh * 32 + g * 8);

  int lr = lane >> 3, lc = lane & 7;
  const u16t* ksrc = kbase + (size_t)lr * 2304 + (size_t)((lc ^ lr) * 8);
  const u16t* vsrc = vtb + (size_t)lr * 1024 + (size_t)((lc ^ lr) * 8);
  int c0 = wave * 2, c1 = wave * 2 + 1;

  auto stage = [&](int kt, int buf) {
    gload_lds16(ksrc + (size_t)(kt + c0 * 8) * 2304, (void*)(Ks[buf] + c0 * 512));
    gload_lds16(ksrc + (size_t)(kt + c1 * 8) * 2304, (void*)(Ks[buf] + c1 * 512));
    gload_lds16(vsrc + (size_t)(c0 * 8) * 1024 + kt, (void*)(Vs[buf] + c0 * 512));
    gload_lds16(vsrc + (size_t)(c1 * 8) * 1024 + kt, (void*)(Vs[buf] + c1 * 512));
  };

  float mA = -1e30f, mB = -1e30f, lA = 0.f, lB = 0.f;
  f32x4 oA[4] = {}, oB[4] = {};
  u16t* Pw = Plds[wave];

  stage(0, 0);
  __syncthreads();

  for (int t = 0; t < 16; ++t) {
    int buf = t & 1;
    if (t < 15) stage((t + 1) * 64, buf ^ 1);

    const u16t* Kb = Ks[buf];
    const u16t* Vb = Vs[buf];

    f32x4 sA[4] = {}, sB[4] = {};
    __builtin_amdgcn_s_setprio(1);
#pragma unroll
    for (int n = 0; n < 4; n++) {
      int row = n * 16 + q;
      short8 k0 = *(const short8*)(Kb + row * 64 + ((g ^ (q & 7)) * 8));
      short8 k1 = *(const short8*)(Kb + row * 64 + (((4 + g) ^ (q & 7)) * 8));
      sA[n] = __builtin_amdgcn_mfma_f32_16x16x32_bf16(k0, qf[0][0], sA[n], 0, 0, 0);
      sA[n] = __builtin_amdgcn_mfma_f32_16x16x32_bf16(k1, qf[0][1], sA[n], 0, 0, 0);
      sB[n] = __builtin_amdgcn_mfma_f32_16x16x32_bf16(k0, qf[1][0], sB[n], 0, 0, 0);
      sB[n] = __builtin_amdgcn_mfma_f32_16x16x32_bf16(k1, qf[1][1], sB[n], 0, 0, 0);
    }
    __builtin_amdgcn_s_setprio(0);

    float alphaA, alphaB;
    {
      float t0 = fmaxf(fmaxf(sA[0][0], sA[0][1]), fmaxf(sA[0][2], sA[0][3]));
      float t1 = fmaxf(fmaxf(sA[1][0], sA[1][1]), fmaxf(sA[1][2], sA[1][3]));
      float t2 = fmaxf(fmaxf(sA[2][0], sA[2][1]), fmaxf(sA[2][2], sA[2][3]));
      float t3 = fmaxf(fmaxf(sA[3][0], sA[3][1]), fmaxf(sA[3][2], sA[3][3]));
      float tm = fmaxf(fmaxf(t0, t1), fmaxf(t2, t3));
      tm = fmaxf(tm, __shfl_xor(tm, 16, 64));
      tm = fmaxf(tm, __shfl_xor(tm, 32, 64));
      float mnew = fmaxf(mA, tm);
      alphaA = __expf((mA - mnew) * 0.125f);
      mA = mnew;
#pragma unroll
      for (int n = 0; n < 4; n++)
#pragma unroll
        for (int i = 0; i < 4; i++) sA[n][i] = __expf((sA[n][i] - mnew) * 0.125f);
      float r0 = (sA[0][0] + sA[0][1]) + (sA[0][2] + sA[0][3]);
      float r1 = (sA[1][0] + sA[1][1]) + (sA[1][2] + sA[1][3]);
      float r2 = (sA[2][0] + sA[2][1]) + (sA[2][2] + sA[2][3]);
      float r3 = (sA[3][0] + sA[3][1]) + (sA[3][2] + sA[3][3]);
      float rs = (r0 + r1) + (r2 + r3);
      rs += __shfl_xor(rs, 16, 64);
      rs += __shfl_xor(rs, 32, 64);
      lA = lA * alphaA + rs;
#pragma unroll
      for (int n = 0; n < 4; n++) {
        uint32_t w0 = cvtpk(sA[n][0], sA[n][1]);
        uint32_t w1 = cvtpk(sA[n][2], sA[n][3]);
        *(uint2*)(Pw + q * 72 + n * 16 + g * 4) = make_uint2(w0, w1);
      }
    }
    {
      float t0 = fmaxf(fmaxf(sB[0][0], sB[0][1]), fmaxf(sB[0][2], sB[0][3]));
      float t1 = fmaxf(fmaxf(sB[1][0], sB[1][1]), fmaxf(sB[1][2], sB[1][3]));
      float t2 = fmaxf(fmaxf(sB[2][0], sB[2][1]), fmaxf(sB[2][2], sB[2][3]));
      float t3 = fmaxf(fmaxf(sB[3][0], sB[3][1]), fmaxf(sB[3][2], sB[3][3]));
      float tm = fmaxf(fmaxf(t0, t1), fmaxf(t2, t3));
      tm = fmaxf(tm, __shfl_xor(tm, 16, 64));
      tm = fmaxf(tm, __shfl_xor(tm, 32, 64));
      float mnew = fmaxf(mB, tm);
      alphaB = __expf((mB - mnew) * 0.125f);
      mB = mnew;
#pragma unroll
      for (int n = 0; n < 4; n++)
#pragma unroll
        for (int i = 0; i < 4; i++) sB[n][i] = __expf((sB[n][i] - mnew) * 0.125f);
      float r0 = (sB[0][0] + sB[0][1]) + (sB[0][2] + sB[0][3]);
      float r1 = (sB[1][0] + sB[1][1]) + (sB[1][2] + sB[1][3]);
      float r2 = (sB[2][0] + sB[2][1]) + (sB[2][2] + sB[2][3]);
      float r3 = (sB[3][0] + sB[3][1]) + (sB[3][2] + sB[3][3]);
      float rs = (r0 + r1) + (r2 + r3);
      rs += __shfl_xor(rs, 16, 64);
      rs += __shfl_xor(rs, 32, 64);
      lB = lB * alphaB + rs;
#pragma unroll
      for (int n = 0; n < 4; n++) {
        uint32_t w0 = cvtpk(sB[n][0], sB[n][1]);
        uint32_t w1 = cvtpk(sB[n][2], sB[n][3]);
        *(uint2*)(Pw + (16 + q) * 72 + n * 16 + g * 4) = make_uint2(w0, w1);
      }
    }

#pragma unroll
    for (int n = 0; n < 4; n++)
#pragma unroll
      for (int i = 0; i < 4; i++) {
        oA[n][i] *= alphaA;
        oB[n][i] *= alphaB;
      }

    short8 pA[2], pB[2];
#pragma unroll
    for (int hh = 0; hh < 2; hh++) {
      pA[hh] = *(const short8*)(Pw + q * 72 + hh * 32 + g * 8);
      pB[hh] = *(const short8*)(Pw + (16 + q) * 72 + hh * 32 + g * 8);
    }
    __builtin_amdgcn_s_setprio(1);
#pragma unroll
    for (int n = 0; n < 4; n++) {
      int row = n * 16 + q;
      short8 v0 = *(const short8*)(Vb + row * 64 + ((g ^ (q & 7)) * 8));
      short8 v1 = *(const short8*)(Vb + row * 64 + (((4 + g) ^ (q & 7)) * 8));
      oA[n] = __builtin_amdgcn_mfma_f32_16x16x32_bf16(v0, pA[0], oA[n], 0, 0, 0);
      oA[n] = __builtin_amdgcn_mfma_f32_16x16x32_bf16(v1, pA[1], oA[n], 0, 0, 0);
      oB[n] = __builtin_amdgcn_mfma_f32_16x16x32_bf16(v0, pB[0], oB[n], 0, 0, 0);
      oB[n] = __builtin_amdgcn_mfma_f32_16x16x32_bf16(v1, pB[1], oB[n], 0, 0, 0);
    }
    __builtin_amdgcn_s_setprio(0);

    __syncthreads();
  }

  float invA = 1.f / lA, invB = 1.f / lB;
  u16t* crowA = ctx + (size_t)(b * 1024 + qt + q) * 768 + h * 64;
  u16t* crowB = ctx + (size_t)(b * 1024 + qt + 16 + q) * 768 + h * 64;
#pragma unroll
  for (int n = 0; n < 4; n++) {
    uint32_t a0 = (uint32_t)f2bf(oA[n][0] * invA) | ((uint32_t)f2bf(oA[n][1] * invA) << 16);
    uint32_t a1 = (uint32_t)f2bf(oA[n][2] * invA) | ((uint32_t)f2bf(oA[n][3] * invA) << 16);
    *(uint32_t*)(crowA + n * 16 + g * 4) = a0;
    *(uint32_t*)(crowA + n * 16 + g * 4 + 2) = a1;
    uint32_t b0 = (uint32_t)f2bf(oB[n][0] * invB) | ((uint32_t)f2bf(oB[n][1] * invB) << 16);
    uint32_t b1 = (uint32_t)f2bf(oB[n][2] * invB) | ((uint32_t)f2bf(oB[n][3] * invB) << 16);
    *(uint32_t*)(crowB + n * 16 + g * 4) = b0;
    *(uint32_t*)(crowB + n * 16 + g * 4 + 2) = b1;
  }
}

// ---------- launch ----------
extern "C" void kernel_launch(void* const* d_in, const int* in_sizes, int n_in,
                              void* d_out, int out_size, void* d_ws, size_t ws_size,
                              hipStream_t stream) {
  const float* x      = (const float*)d_in[0];
  const float* ln1_g  = (const float*)d_in[1];
  const float* ln1_b  = (const float*)d_in[2];
  const float* qkv_w  = (const float*)d_in[3];
  const float* proj_w = (const float*)d_in[4];
  const float* proj_b = (const float*)d_in[5];
  const float* ln2_g  = (const float*)d_in[6];
  const float* ln2_b  = (const float*)d_in[7];
  const float* fc1_w  = (const float*)d_in[8];
  const float* fc1_b  = (const float*)d_in[9];
  const float* fc2_w  = (const float*)d_in[10];
  const float* fc2_b  = (const float*)d_in[11];

  char* ws = (char*)d_ws;
  u16t* h1   = (u16t*)(ws + 0);           // 8192x768 bf16 (ln1 out; REUSED as vt; then ln2 out)
  u16t* qkvb = (u16t*)(ws + 12582912);    // 8192x2304 bf16
  u16t* ctx  = (u16t*)(ws + 50331648);    // 8192x768 bf16
  float* x2  = (float*)(ws + 62914560);   // 8192x768 f32
  u16t* hid  = (u16t*)(ws + 88080384);    // 8192x3072 bf16
  u16t* wq   = (u16t*)(ws + 138412032);   // 2304x768 bf16
  u16t* wp   = (u16t*)(ws + 141950976);   // 768x768 bf16
  u16t* w1   = (u16t*)(ws + 143130624);   // 3072x768 bf16
  u16t* w2   = (u16t*)(ws + 147849216);   // 768x3072 bf16
  u16t* vtb  = h1;                        // 96x64x1024 bf16, lifetime-disjoint
  float* out = (float*)d_out;

  cvt_bf16_kernel<<<864, 256, 0, stream>>>(qkv_w, wq, 221184);
  cvt_bf16_kernel<<<288, 256, 0, stream>>>(proj_w, wp, 73728);
  cvt_bf16_kernel<<<1152, 256, 0, stream>>>(fc1_w, w1, 294912);
  cvt_bf16_kernel<<<1152, 256, 0, stream>>>(fc2_w, w2, 294912);

  ln_kernel<<<8192, 256, 0, stream>>>(x, ln1_g, ln1_b, h1);
  // qkv: M=8192(nbm=64), N=2304 (nbn=9 @ BN=256) -> 576 blocks
  gemm5<0><<<576, 512, 0, stream>>>(h1, wq, qkvb, nullptr, nullptr, 2304, 768, 64);
  vtrans_kernel<<<dim3(96, 16), 256, 0, stream>>>(qkvb, vtb);
  attn_kernel<<<768, 256, 0, stream>>>(qkvb, vtb, ctx);
  // proj: N=768 (nbn=6 @ BN=128) -> 384 blocks
  gemm4<1><<<384, 256, 0, stream>>>(ctx, wp, x2, proj_b, x, 768, 768, 64);
  ln_kernel<<<8192, 256, 0, stream>>>(x2, ln2_g, ln2_b, h1);
  // fc1: N=3072 (nbn=12 @ BN=256) -> 768 blocks
  gemm5<2><<<768, 512, 0, stream>>>(h1, w1, hid, fc1_b, nullptr, 3072, 768, 64);
  // fc2: N=768 (nbn=6 @ BN=128), K=3072 -> 384 blocks
  gemm4<1><<<384, 256, 0, stream>>>(hid, w2, out, fc2_b, x2, 768, 3072, 64);
}

// Round 10
// 471.369 us; speedup vs baseline: 1.0357x; 1.0357x over previous
//
#include <hip/hip_runtime.h>
#include <cstdint>

typedef __attribute__((ext_vector_type(8))) short short8;
typedef __attribute__((ext_vector_type(4))) float f32x4;
typedef unsigned short u16t;

// ---------- helpers ----------
__device__ __forceinline__ u16t f2bf(float f) {
  uint32_t u = __float_as_uint(f);
  u += 0x7fffu + ((u >> 16) & 1u);   // RNE
  return (u16t)(u >> 16);
}

__device__ __forceinline__ uint32_t cvtpk(float lo, float hi) {
  uint32_t r;
  asm("v_cvt_pk_bf16_f32 %0, %1, %2" : "=v"(r) : "v"(lo), "v"(hi));
  return r;
}

__device__ __forceinline__ void gload_lds16(const void* g, void* l) {
  __builtin_amdgcn_global_load_lds(
      (const __attribute__((address_space(1))) void*)g,
      (__attribute__((address_space(3))) void*)l, 16, 0, 0);
}

__device__ __forceinline__ float gelu_exact(float v) {
  return 0.5f * v * (1.0f + erff(v * 0.70710678118f));
}

// ---------- f32 -> bf16 convert ----------
__global__ __launch_bounds__(256) void cvt_bf16_kernel(const float* __restrict__ in,
                                                       u16t* __restrict__ out, int n8) {
  int i = blockIdx.x * 256 + threadIdx.x;
  if (i >= n8) return;
  const float4* p = (const float4*)in + (size_t)i * 2;
  float4 a = p[0], b = p[1];
  union { short8 v; u16t e[8]; } r;
  r.e[0] = f2bf(a.x); r.e[1] = f2bf(a.y); r.e[2] = f2bf(a.z); r.e[3] = f2bf(a.w);
  r.e[4] = f2bf(b.x); r.e[5] = f2bf(b.y); r.e[6] = f2bf(b.z); r.e[7] = f2bf(b.w);
  *((short8*)out + i) = r.v;
}

// ---------- LayerNorm (row = 768 f32) -> bf16 ----------
__global__ __launch_bounds__(256) void ln_kernel(const float* __restrict__ x,
                                                 const float* __restrict__ g,
                                                 const float* __restrict__ b,
                                                 u16t* __restrict__ out) {
  int row = blockIdx.x, tid = threadIdx.x;
  int wave = tid >> 6, lane = tid & 63;
  const float* xr = x + (size_t)row * 768;
  float v0 = xr[tid], v1 = xr[tid + 256], v2 = xr[tid + 512];
  float s = v0 + v1 + v2;
  float q = v0 * v0 + v1 * v1 + v2 * v2;
#pragma unroll
  for (int m = 32; m >= 1; m >>= 1) {
    s += __shfl_xor(s, m, 64);
    q += __shfl_xor(q, m, 64);
  }
  __shared__ float red[8];
  if (lane == 0) { red[wave] = s; red[4 + wave] = q; }
  __syncthreads();
  s = red[0] + red[1] + red[2] + red[3];
  q = red[4] + red[5] + red[6] + red[7];
  float mu = s * (1.0f / 768.0f);
  float var = q * (1.0f / 768.0f) - mu * mu;
  float rs = rsqrtf(var + 1e-5f);
  u16t* orow = out + (size_t)row * 768;
  orow[tid]       = f2bf((v0 - mu) * rs * g[tid]       + b[tid]);
  orow[tid + 256] = f2bf((v1 - mu) * rs * g[tid + 256] + b[tid + 256]);
  orow[tid + 512] = f2bf((v2 - mu) * rs * g[tid + 512] + b[tid + 512]);
}

// ---------- GEMM: C[M,N] = A[M,K] @ W[N,K]^T  (bf16 in, fp32 acc) ----------
// R5 structure (measured best): single-buffer LDS, serial 2-barrier loop,
// natural 2-D grid (bn fast) — concurrency-driven L3 reuse, no swizzle.
// Change vs R5: launch_bounds MINB=4 (occupancy headroom) + packed epilogue.
// EPI 0: bf16 store; EPI 1: f32 store acc+bias+res; EPI 2: bf16 gelu(acc+bias)
template <int EPI, int BM>
__global__ __launch_bounds__(256, 4) void gemm_bt(const u16t* __restrict__ A,
                                                  const u16t* __restrict__ W,
                                                  void* __restrict__ Cout,
                                                  const float* __restrict__ bias,
                                                  const float* __restrict__ res,
                                                  int M, int N, int K) {
  __shared__ __align__(16) u16t As[BM * 64];
  __shared__ __align__(16) u16t Bs[128 * 64];
  constexpr int MF = BM / 32;
  int tid = threadIdx.x;
  int wave = tid >> 6, lane = tid & 63;
  int wr = wave >> 1, wc = wave & 1;
  int q = lane & 15, g = lane >> 4;
  int bm = blockIdx.y * BM;
  int bn = blockIdx.x * 128;
  f32x4 acc[MF][4] = {};

  int lr = lane >> 3, lc = lane & 7;
  const u16t* Abase = A + (size_t)(bm + lr) * K + ((lc ^ lr) * 8);
  const u16t* Wbase = W + (size_t)(bn + lr) * K + ((lc ^ lr) * 8);

  int NT = K >> 6;
  for (int t = 0; t < NT; ++t) {
    int kt = t * 64;
#pragma unroll
    for (int i = 0; i < BM / 32; i++) {
      int chunk = wave * (BM / 32) + i;
      gload_lds16(Abase + (size_t)(chunk * 8) * K + kt, (void*)(As + chunk * 512));
    }
#pragma unroll
    for (int i = 0; i < 4; i++) {
      int chunk = wave * 4 + i;
      gload_lds16(Wbase + (size_t)(chunk * 8) * K + kt, (void*)(Bs + chunk * 512));
    }
    __syncthreads();

    short8 af[MF][2], bfr[4][2];
#pragma unroll
    for (int m = 0; m < MF; m++) {
      int row = wr * (BM / 2) + m * 16 + q;
#pragma unroll
      for (int s = 0; s < 2; s++)
        af[m][s] = *(const short8*)(As + row * 64 + (((s * 4 + g) ^ (row & 7)) * 8));
    }
#pragma unroll
    for (int n = 0; n < 4; n++) {
      int row = wc * 64 + n * 16 + q;
#pragma unroll
      for (int s = 0; s < 2; s++)
        bfr[n][s] = *(const short8*)(Bs + row * 64 + (((s * 4 + g) ^ (row & 7)) * 8));
    }
    __builtin_amdgcn_s_setprio(1);
#pragma unroll
    for (int m = 0; m < MF; m++)
#pragma unroll
      for (int n = 0; n < 4; n++) {
        acc[m][n] = __builtin_amdgcn_mfma_f32_16x16x32_bf16(bfr[n][0], af[m][0], acc[m][n], 0, 0, 0);
        acc[m][n] = __builtin_amdgcn_mfma_f32_16x16x32_bf16(bfr[n][1], af[m][1], acc[m][n], 0, 0, 0);
      }
    __builtin_amdgcn_s_setprio(0);
    __syncthreads();
  }

  // epilogue: lane owns row m (fixed), 4 consecutive cols -> packed stores
#pragma unroll
  for (int m = 0; m < MF; m++) {
    int r = bm + wr * (BM / 2) + m * 16 + q;
#pragma unroll
    for (int n = 0; n < 4; n++) {
      int c = bn + wc * 64 + n * 16 + g * 4;
      f32x4 v = acc[m][n];
      if constexpr (EPI == 0) {
        uint2 pk = make_uint2(cvtpk(v[0], v[1]), cvtpk(v[2], v[3]));
        *(uint2*)((u16t*)Cout + (size_t)r * N + c) = pk;
      } else if constexpr (EPI == 1) {
        const float4 bv = *(const float4*)(bias + c);
        const float4 rv = *(const float4*)(res + (size_t)r * N + c);
        float4 o;
        o.x = v[0] + bv.x + rv.x; o.y = v[1] + bv.y + rv.y;
        o.z = v[2] + bv.z + rv.z; o.w = v[3] + bv.w + rv.w;
        *(float4*)((float*)Cout + (size_t)r * N + c) = o;
      } else {
        const float4 bv = *(const float4*)(bias + c);
        uint2 pk = make_uint2(cvtpk(gelu_exact(v[0] + bv.x), gelu_exact(v[1] + bv.y)),
                              cvtpk(gelu_exact(v[2] + bv.z), gelu_exact(v[3] + bv.w)));
        *(uint2*)((u16t*)Cout + (size_t)r * N + c) = pk;
      }
    }
  }
}

// ---------- V transpose: qkvb V-part -> vt[head][64][1024] ----------
__global__ __launch_bounds__(256) void vtrans_kernel(const u16t* __restrict__ qkv,
                                                     u16t* __restrict__ vt) {
  __shared__ u16t T[64][66];
  int h = blockIdx.x % 12, bb = blockIdx.x / 12, kt = blockIdx.y * 64;
  int t = threadIdx.x;
  int r = t >> 2, dc = t & 3;
  const u16t* src = qkv + (size_t)(bb * 1024 + kt + r) * 2304 + 1536 + h * 64 + dc * 16;
  union { uint4 u[2]; u16t e[16]; uint32_t w[8]; } buf;
  buf.u[0] = *(const uint4*)src;
  buf.u[1] = *(const uint4*)(src + 8);
#pragma unroll
  for (int j = 0; j < 8; j++)
    *(uint32_t*)&T[r][dc * 16 + 2 * j] = buf.w[j];
  __syncthreads();
  int d = t >> 2, kc = t & 3;
  union { uint4 u[2]; u16t e[16]; } o;
#pragma unroll
  for (int j = 0; j < 16; j++) o.e[j] = T[kc * 16 + j][d];
  u16t* dst = vt + ((size_t)blockIdx.x * 64 + d) * 1024 + kt + kc * 16;
  *(uint4*)dst = o.u[0];
  *(uint4*)(dst + 8) = o.u[1];
}

// ---------- flash attention: block-shared LDS staging + 2-phase pipeline ----------
__global__ __launch_bounds__(256, 3) void attn_kernel(const u16t* __restrict__ qkv,
                                                      const u16t* __restrict__ vt,
                                                      u16t* __restrict__ ctx) {
  __shared__ __align__(16) u16t Ks[2][64 * 64];
  __shared__ __align__(16) u16t Vs[2][64 * 64];
  __shared__ __align__(16) u16t Plds[4][32 * 72];
  int tid = threadIdx.x;
  int wave = tid >> 6, lane = tid & 63;
  int q = lane & 15, g = lane >> 4;

  int bid = blockIdx.x;
  int xcd = bid & 7, j = bid >> 3;
  int head = xcd + 8 * (j >> 3);
  int qt = (j & 7) * 128 + wave * 32;
  int b = head / 12, h = head % 12;

  const u16t* base = qkv + (size_t)b * 1024 * 2304 + h * 64;
  const u16t* kbase = base + 768;
  const u16t* vtb = vt + (size_t)head * 64 * 1024;

  short8 qf[2][2];
#pragma unroll
  for (int hf = 0; hf < 2; hf++)
#pragma unroll
    for (int hh = 0; hh < 2; hh++)
      qf[hf][hh] = *(const short8*)(base + (size_t)(qt + hf * 16 + q) * 2304 + hh * 32 + g * 8);

  int lr = lane >> 3, lc = lane & 7;
  const u16t* ksrc = kbase + (size_t)lr * 2304 + (size_t)((lc ^ lr) * 8);
  const u16t* vsrc = vtb + (size_t)lr * 1024 + (size_t)((lc ^ lr) * 8);
  int c0 = wave * 2, c1 = wave * 2 + 1;

  auto stage = [&](int kt, int buf) {
    gload_lds16(ksrc + (size_t)(kt + c0 * 8) * 2304, (void*)(Ks[buf] + c0 * 512));
    gload_lds16(ksrc + (size_t)(kt + c1 * 8) * 2304, (void*)(Ks[buf] + c1 * 512));
    gload_lds16(vsrc + (size_t)(c0 * 8) * 1024 + kt, (void*)(Vs[buf] + c0 * 512));
    gload_lds16(vsrc + (size_t)(c1 * 8) * 1024 + kt, (void*)(Vs[buf] + c1 * 512));
  };

  float mA = -1e30f, mB = -1e30f, lA = 0.f, lB = 0.f;
  f32x4 oA[4] = {}, oB[4] = {};
  u16t* Pw = Plds[wave];

  stage(0, 0);
  __syncthreads();

  for (int t = 0; t < 16; ++t) {
    int buf = t & 1;
    if (t < 15) stage((t + 1) * 64, buf ^ 1);

    const u16t* Kb = Ks[buf];
    const u16t* Vb = Vs[buf];

    f32x4 sA[4] = {}, sB[4] = {};
    __builtin_amdgcn_s_setprio(1);
#pragma unroll
    for (int n = 0; n < 4; n++) {
      int row = n * 16 + q;
      short8 k0 = *(const short8*)(Kb + row * 64 + ((g ^ (q & 7)) * 8));
      short8 k1 = *(const short8*)(Kb + row * 64 + (((4 + g) ^ (q & 7)) * 8));
      sA[n] = __builtin_amdgcn_mfma_f32_16x16x32_bf16(k0, qf[0][0], sA[n], 0, 0, 0);
      sA[n] = __builtin_amdgcn_mfma_f32_16x16x32_bf16(k1, qf[0][1], sA[n], 0, 0, 0);
      sB[n] = __builtin_amdgcn_mfma_f32_16x16x32_bf16(k0, qf[1][0], sB[n], 0, 0, 0);
      sB[n] = __builtin_amdgcn_mfma_f32_16x16x32_bf16(k1, qf[1][1], sB[n], 0, 0, 0);
    }
    __builtin_amdgcn_s_setprio(0);

    float alphaA, alphaB;
    {
      float t0 = fmaxf(fmaxf(sA[0][0], sA[0][1]), fmaxf(sA[0][2], sA[0][3]));
      float t1 = fmaxf(fmaxf(sA[1][0], sA[1][1]), fmaxf(sA[1][2], sA[1][3]));
      float t2 = fmaxf(fmaxf(sA[2][0], sA[2][1]), fmaxf(sA[2][2], sA[2][3]));
      float t3 = fmaxf(fmaxf(sA[3][0], sA[3][1]), fmaxf(sA[3][2], sA[3][3]));
      float tm = fmaxf(fmaxf(t0, t1), fmaxf(t2, t3));
      tm = fmaxf(tm, __shfl_xor(tm, 16, 64));
      tm = fmaxf(tm, __shfl_xor(tm, 32, 64));
      float mnew = fmaxf(mA, tm);
      alphaA = __expf((mA - mnew) * 0.125f);
      mA = mnew;
#pragma unroll
      for (int n = 0; n < 4; n++)
#pragma unroll
        for (int i = 0; i < 4; i++) sA[n][i] = __expf((sA[n][i] - mnew) * 0.125f);
      float r0 = (sA[0][0] + sA[0][1]) + (sA[0][2] + sA[0][3]);
      float r1 = (sA[1][0] + sA[1][1]) + (sA[1][2] + sA[1][3]);
      float r2 = (sA[2][0] + sA[2][1]) + (sA[2][2] + sA[2][3]);
      float r3 = (sA[3][0] + sA[3][1]) + (sA[3][2] + sA[3][3]);
      float rs = (r0 + r1) + (r2 + r3);
      rs += __shfl_xor(rs, 16, 64);
      rs += __shfl_xor(rs, 32, 64);
      lA = lA * alphaA + rs;
#pragma unroll
      for (int n = 0; n < 4; n++) {
        uint32_t w0 = cvtpk(sA[n][0], sA[n][1]);
        uint32_t w1 = cvtpk(sA[n][2], sA[n][3]);
        *(uint2*)(Pw + q * 72 + n * 16 + g * 4) = make_uint2(w0, w1);
      }
    }
    {
      float t0 = fmaxf(fmaxf(sB[0][0], sB[0][1]), fmaxf(sB[0][2], sB[0][3]));
      float t1 = fmaxf(fmaxf(sB[1][0], sB[1][1]), fmaxf(sB[1][2], sB[1][3]));
      float t2 = fmaxf(fmaxf(sB[2][0], sB[2][1]), fmaxf(sB[2][2], sB[2][3]));
      float t3 = fmaxf(fmaxf(sB[3][0], sB[3][1]), fmaxf(sB[3][2], sB[3][3]));
      float tm = fmaxf(fmaxf(t0, t1), fmaxf(t2, t3));
      tm = fmaxf(tm, __shfl_xor(tm, 16, 64));
      tm = fmaxf(tm, __shfl_xor(tm, 32, 64));
      float mnew = fmaxf(mB, tm);
      alphaB = __expf((mB - mnew) * 0.125f);
      mB = mnew;
#pragma unroll
      for (int n = 0; n < 4; n++)
#pragma unroll
        for (int i = 0; i < 4; i++) sB[n][i] = __expf((sB[n][i] - mnew) * 0.125f);
      float r0 = (sB[0][0] + sB[0][1]) + (sB[0][2] + sB[0][3]);
      float r1 = (sB[1][0] + sB[1][1]) + (sB[1][2] + sB[1][3]);
      float r2 = (sB[2][0] + sB[2][1]) + (sB[2][2] + sB[2][3]);
      float r3 = (sB[3][0] + sB[3][1]) + (sB[3][2] + sB[3][3]);
      float rs = (r0 + r1) + (r2 + r3);
      rs += __shfl_xor(rs, 16, 64);
      rs += __shfl_xor(rs, 32, 64);
      lB = lB * alphaB + rs;
#pragma unroll
      for (int n = 0; n < 4; n++) {
        uint32_t w0 = cvtpk(sB[n][0], sB[n][1]);
        uint32_t w1 = cvtpk(sB[n][2], sB[n][3]);
        *(uint2*)(Pw + (16 + q) * 72 + n * 16 + g * 4) = make_uint2(w0, w1);
      }
    }

#pragma unroll
    for (int n = 0; n < 4; n++)
#pragma unroll
      for (int i = 0; i < 4; i++) {
        oA[n][i] *= alphaA;
        oB[n][i] *= alphaB;
      }

    short8 pA[2], pB[2];
#pragma unroll
    for (int hh = 0; hh < 2; hh++) {
      pA[hh] = *(const short8*)(Pw + q * 72 + hh * 32 + g * 8);
      pB[hh] = *(const short8*)(Pw + (16 + q) * 72 + hh * 32 + g * 8);
    }
    __builtin_amdgcn_s_setprio(1);
#pragma unroll
    for (int n = 0; n < 4; n++) {
      int row = n * 16 + q;
      short8 v0 = *(const short8*)(Vb + row * 64 + ((g ^ (q & 7)) * 8));
      short8 v1 = *(const short8*)(Vb + row * 64 + (((4 + g) ^ (q & 7)) * 8));
      oA[n] = __builtin_amdgcn_mfma_f32_16x16x32_bf16(v0, pA[0], oA[n], 0, 0, 0);
      oA[n] = __builtin_amdgcn_mfma_f32_16x16x32_bf16(v1, pA[1], oA[n], 0, 0, 0);
      oB[n] = __builtin_amdgcn_mfma_f32_16x16x32_bf16(v0, pB[0], oB[n], 0, 0, 0);
      oB[n] = __builtin_amdgcn_mfma_f32_16x16x32_bf16(v1, pB[1], oB[n], 0, 0, 0);
    }
    __builtin_amdgcn_s_setprio(0);

    __syncthreads();
  }

  float invA = 1.f / lA, invB = 1.f / lB;
  u16t* crowA = ctx + (size_t)(b * 1024 + qt + q) * 768 + h * 64;
  u16t* crowB = ctx + (size_t)(b * 1024 + qt + 16 + q) * 768 + h * 64;
#pragma unroll
  for (int n = 0; n < 4; n++) {
    uint32_t a0 = (uint32_t)f2bf(oA[n][0] * invA) | ((uint32_t)f2bf(oA[n][1] * invA) << 16);
    uint32_t a1 = (uint32_t)f2bf(oA[n][2] * invA) | ((uint32_t)f2bf(oA[n][3] * invA) << 16);
    *(uint32_t*)(crowA + n * 16 + g * 4) = a0;
    *(uint32_t*)(crowA + n * 16 + g * 4 + 2) = a1;
    uint32_t b0 = (uint32_t)f2bf(oB[n][0] * invB) | ((uint32_t)f2bf(oB[n][1] * invB) << 16);
    uint32_t b1 = (uint32_t)f2bf(oB[n][2] * invB) | ((uint32_t)f2bf(oB[n][3] * invB) << 16);
    *(uint32_t*)(crowB + n * 16 + g * 4) = b0;
    *(uint32_t*)(crowB + n * 16 + g * 4 + 2) = b1;
  }
}

// ---------- launch ----------
extern "C" void kernel_launch(void* const* d_in, const int* in_sizes, int n_in,
                              void* d_out, int out_size, void* d_ws, size_t ws_size,
                              hipStream_t stream) {
  const float* x      = (const float*)d_in[0];
  const float* ln1_g  = (const float*)d_in[1];
  const float* ln1_b  = (const float*)d_in[2];
  const float* qkv_w  = (const float*)d_in[3];
  const float* proj_w = (const float*)d_in[4];
  const float* proj_b = (const float*)d_in[5];
  const float* ln2_g  = (const float*)d_in[6];
  const float* ln2_b  = (const float*)d_in[7];
  const float* fc1_w  = (const float*)d_in[8];
  const float* fc1_b  = (const float*)d_in[9];
  const float* fc2_w  = (const float*)d_in[10];
  const float* fc2_b  = (const float*)d_in[11];

  char* ws = (char*)d_ws;
  u16t* h1   = (u16t*)(ws + 0);           // 8192x768 bf16 (ln1 out; REUSED as vt; then ln2 out)
  u16t* qkvb = (u16t*)(ws + 12582912);    // 8192x2304 bf16
  u16t* ctx  = (u16t*)(ws + 50331648);    // 8192x768 bf16
  float* x2  = (float*)(ws + 62914560);   // 8192x768 f32
  u16t* hid  = (u16t*)(ws + 88080384);    // 8192x3072 bf16
  u16t* wq   = (u16t*)(ws + 138412032);   // 2304x768 bf16
  u16t* wp   = (u16t*)(ws + 141950976);   // 768x768 bf16
  u16t* w1   = (u16t*)(ws + 143130624);   // 3072x768 bf16
  u16t* w2   = (u16t*)(ws + 147849216);   // 768x3072 bf16
  u16t* vtb  = h1;                        // 96x64x1024 bf16, lifetime-disjoint
  float* out = (float*)d_out;

  cvt_bf16_kernel<<<864, 256, 0, stream>>>(qkv_w, wq, 221184);
  cvt_bf16_kernel<<<288, 256, 0, stream>>>(proj_w, wp, 73728);
  cvt_bf16_kernel<<<1152, 256, 0, stream>>>(fc1_w, w1, 294912);
  cvt_bf16_kernel<<<1152, 256, 0, stream>>>(fc2_w, w2, 294912);

  ln_kernel<<<8192, 256, 0, stream>>>(x, ln1_g, ln1_b, h1);
  gemm_bt<0, 128><<<dim3(18, 64), 256, 0, stream>>>(h1, wq, qkvb, nullptr, nullptr, 8192, 2304, 768);
  vtrans_kernel<<<dim3(96, 16), 256, 0, stream>>>(qkvb, vtb);
  attn_kernel<<<768, 256, 0, stream>>>(qkvb, vtb, ctx);
  gemm_bt<1, 64><<<dim3(6, 128), 256, 0, stream>>>(ctx, wp, x2, proj_b, x, 8192, 768, 768);
  ln_kernel<<<8192, 256, 0, stream>>>(x2, ln2_g, ln2_b, h1);
  gemm_bt<2, 128><<<dim3(24, 64), 256, 0, stream>>>(h1, w1, hid, fc1_b, nullptr, 8192, 3072, 768);
  gemm_bt<1, 64><<<dim3(6, 128), 256, 0, stream>>>(hid, w2, out, fc2_b, x2, 8192, 768, 3072);
}

// Round 11
// 420.458 us; speedup vs baseline: 1.1611x; 1.1211x over previous
//
#include <hip/hip_runtime.h>
#include <cstdint>

typedef __attribute__((ext_vector_type(8))) short short8;
typedef __attribute__((ext_vector_type(4))) float f32x4;
typedef unsigned short u16t;

// ---------- helpers ----------
__device__ __forceinline__ u16t f2bf(float f) {
  uint32_t u = __float_as_uint(f);
  u += 0x7fffu + ((u >> 16) & 1u);   // RNE
  return (u16t)(u >> 16);
}

__device__ __forceinline__ uint32_t cvtpk(float lo, float hi) {
  uint32_t r;
  asm("v_cvt_pk_bf16_f32 %0, %1, %2" : "=v"(r) : "v"(lo), "v"(hi));
  return r;
}

__device__ __forceinline__ void gload_lds16(const void* g, void* l) {
  __builtin_amdgcn_global_load_lds(
      (const __attribute__((address_space(1))) void*)g,
      (__attribute__((address_space(3))) void*)l, 16, 0, 0);
}

__device__ __forceinline__ float gelu_exact(float v) {
  return 0.5f * v * (1.0f + erff(v * 0.70710678118f));
}

// ---------- f32 -> bf16 convert ----------
__global__ __launch_bounds__(256) void cvt_bf16_kernel(const float* __restrict__ in,
                                                       u16t* __restrict__ out, int n8) {
  int i = blockIdx.x * 256 + threadIdx.x;
  if (i >= n8) return;
  const float4* p = (const float4*)in + (size_t)i * 2;
  float4 a = p[0], b = p[1];
  union { short8 v; u16t e[8]; } r;
  r.e[0] = f2bf(a.x); r.e[1] = f2bf(a.y); r.e[2] = f2bf(a.z); r.e[3] = f2bf(a.w);
  r.e[4] = f2bf(b.x); r.e[5] = f2bf(b.y); r.e[6] = f2bf(b.z); r.e[7] = f2bf(b.w);
  *((short8*)out + i) = r.v;
}

// ---------- LayerNorm (row = 768 f32) -> bf16 ----------
__global__ __launch_bounds__(256) void ln_kernel(const float* __restrict__ x,
                                                 const float* __restrict__ g,
                                                 const float* __restrict__ b,
                                                 u16t* __restrict__ out) {
  int row = blockIdx.x, tid = threadIdx.x;
  int wave = tid >> 6, lane = tid & 63;
  const float* xr = x + (size_t)row * 768;
  float v0 = xr[tid], v1 = xr[tid + 256], v2 = xr[tid + 512];
  float s = v0 + v1 + v2;
  float q = v0 * v0 + v1 * v1 + v2 * v2;
#pragma unroll
  for (int m = 32; m >= 1; m >>= 1) {
    s += __shfl_xor(s, m, 64);
    q += __shfl_xor(q, m, 64);
  }
  __shared__ float red[8];
  if (lane == 0) { red[wave] = s; red[4 + wave] = q; }
  __syncthreads();
  s = red[0] + red[1] + red[2] + red[3];
  q = red[4] + red[5] + red[6] + red[7];
  float mu = s * (1.0f / 768.0f);
  float var = q * (1.0f / 768.0f) - mu * mu;
  float rs = rsqrtf(var + 1e-5f);
  u16t* orow = out + (size_t)row * 768;
  orow[tid]       = f2bf((v0 - mu) * rs * g[tid]       + b[tid]);
  orow[tid + 256] = f2bf((v1 - mu) * rs * g[tid + 256] + b[tid + 256]);
  orow[tid + 512] = f2bf((v2 - mu) * rs * g[tid + 512] + b[tid + 512]);
}

// ---------- gemm256: C[M,N] = A[M,K] @ W[N,K]^T, tile 256 x BNT, BK=32 ----------
// 512 thr = 8 waves (2M x 4N). 3 LDS buffers; depth-2 counted-vmcnt pipeline:
// iter t: vmcnt(L) [t landed, t+1 in flight] -> s_barrier (publish; each wave
// waited its OWN loads) -> stage(t+2) into buf[(t+2)%3] (WAR-safe: its readers
// finished before the barrier) -> swizzled ds_read -> 32 MFMA.
// XOR swizzle both-sides (rule 21): LDS slot ls of row holds global kslot
// ls ^ ((row>>1)&3); 2-way bank aliasing (free).
// EPI 0: bf16; EPI 1: f32 acc+bias+res; EPI 2: bf16 gelu(acc+bias)
template <int EPI, int BNT>
__global__ __launch_bounds__(512, 2) void gemm256(const u16t* __restrict__ A,
                                                  const u16t* __restrict__ W,
                                                  void* __restrict__ Cout,
                                                  const float* __restrict__ bias,
                                                  const float* __restrict__ res,
                                                  int N, int K) {
  constexpr int NF = BNT / 64;          // N-fragments per wave (4 or 2)
  constexpr int BCH = BNT / 16;         // B chunks (16 or 8)
  constexpr int LPI = 2 + BCH / 8;      // loads per thread per iter (4 or 3)
  __shared__ __align__(16) u16t As[3][256 * 32];
  __shared__ __align__(16) u16t Bs[3][BNT * 32];
  int tid = threadIdx.x;
  int wid = tid >> 6, lane = tid & 63;
  int wr = wid >> 2, wc = wid & 3;
  int q = lane & 15, g = lane >> 4;
  int bm = blockIdx.y * 256, bn = blockIdx.x * BNT;

  f32x4 acc[8][NF] = {};

  // staging: lane -> (row-in-chunk lr, 16B slot ls); source k pre-swizzled
  int lr = lane >> 2, ls = lane & 3;
  int kof = (ls ^ ((lr >> 1) & 3)) * 8;
  const u16t* Asrc = A + (size_t)(bm + lr) * K + kof;
  const u16t* Wsrc = W + (size_t)(bn + lr) * K + kof;
  int ca = wid * 2;                     // this wave's 2 A chunks
  int cb = (BCH == 16) ? wid * 2 : wid; // 2 or 1 B chunks

  auto stage = [&](int t, int db) {
    int kt = t * 32;
    gload_lds16(Asrc + (size_t)(ca * 16) * K + kt, (void*)(As[db] + ca * 512));
    gload_lds16(Asrc + (size_t)(ca * 16 + 16) * K + kt, (void*)(As[db] + ca * 512 + 512));
    gload_lds16(Wsrc + (size_t)(cb * 16) * K + kt, (void*)(Bs[db] + cb * 512));
    if constexpr (BCH == 16)
      gload_lds16(Wsrc + (size_t)(cb * 16 + 16) * K + kt, (void*)(Bs[db] + cb * 512 + 512));
  };

  stage(0, 0);
  stage(1, 1);

  int NT = K >> 5;
  int swz = (g ^ ((q >> 1) & 3)) * 8;   // read-side XOR (same for A and B rows)
  for (int t = 0; t < NT; ++t) {
    int db = t % 3;
    if (t + 1 < NT) {
      if constexpr (LPI == 4) asm volatile("s_waitcnt vmcnt(4)" ::: "memory");
      else                    asm volatile("s_waitcnt vmcnt(3)" ::: "memory");
    } else {
      asm volatile("s_waitcnt vmcnt(0)" ::: "memory");
    }
    __builtin_amdgcn_s_barrier();       // raw barrier: no waitcnt drain
    if (t + 2 < NT) stage(t + 2, (t + 2) % 3);

    const u16t* Ab = As[db];
    const u16t* Bb = Bs[db];
    short8 bf[NF];
#pragma unroll
    for (int n = 0; n < NF; n++)
      bf[n] = *(const short8*)(Bb + (wc * (BNT / 4) + n * 16 + q) * 32 + swz);
    __builtin_amdgcn_s_setprio(1);
#pragma unroll
    for (int m = 0; m < 8; m++) {
      short8 af = *(const short8*)(Ab + (wr * 128 + m * 16 + q) * 32 + swz);
#pragma unroll
      for (int n = 0; n < NF; n++)
        acc[m][n] = __builtin_amdgcn_mfma_f32_16x16x32_bf16(bf[n], af, acc[m][n], 0, 0, 0);
    }
    __builtin_amdgcn_s_setprio(0);
  }

  // epilogue: lane owns row r (fixed), 4 consecutive cols per (n,g)
#pragma unroll
  for (int m = 0; m < 8; m++) {
    int r = bm + wr * 128 + m * 16 + q;
#pragma unroll
    for (int n = 0; n < NF; n++) {
      int c = bn + wc * (BNT / 4) + n * 16 + g * 4;
      f32x4 v = acc[m][n];
      if constexpr (EPI == 0) {
        uint2 pk = make_uint2(cvtpk(v[0], v[1]), cvtpk(v[2], v[3]));
        *(uint2*)((u16t*)Cout + (size_t)r * N + c) = pk;
      } else if constexpr (EPI == 1) {
        const float4 bv = *(const float4*)(bias + c);
        const float4 rv = *(const float4*)(res + (size_t)r * N + c);
        float4 o;
        o.x = v[0] + bv.x + rv.x; o.y = v[1] + bv.y + rv.y;
        o.z = v[2] + bv.z + rv.z; o.w = v[3] + bv.w + rv.w;
        *(float4*)((float*)Cout + (size_t)r * N + c) = o;
      } else {
        const float4 bv = *(const float4*)(bias + c);
        uint2 pk = make_uint2(cvtpk(gelu_exact(v[0] + bv.x), gelu_exact(v[1] + bv.y)),
                              cvtpk(gelu_exact(v[2] + bv.z), gelu_exact(v[3] + bv.w)));
        *(uint2*)((u16t*)Cout + (size_t)r * N + c) = pk;
      }
    }
  }
}

// ---------- V transpose: qkvb V-part -> vt[head][64][1024] ----------
__global__ __launch_bounds__(256) void vtrans_kernel(const u16t* __restrict__ qkv,
                                                     u16t* __restrict__ vt) {
  __shared__ u16t T[64][66];
  int h = blockIdx.x % 12, bb = blockIdx.x / 12, kt = blockIdx.y * 64;
  int t = threadIdx.x;
  int r = t >> 2, dc = t & 3;
  const u16t* src = qkv + (size_t)(bb * 1024 + kt + r) * 2304 + 1536 + h * 64 + dc * 16;
  union { uint4 u[2]; u16t e[16]; uint32_t w[8]; } buf;
  buf.u[0] = *(const uint4*)src;
  buf.u[1] = *(const uint4*)(src + 8);
#pragma unroll
  for (int j = 0; j < 8; j++)
    *(uint32_t*)&T[r][dc * 16 + 2 * j] = buf.w[j];
  __syncthreads();
  int d = t >> 2, kc = t & 3;
  union { uint4 u[2]; u16t e[16]; } o;
#pragma unroll
  for (int j = 0; j < 16; j++) o.e[j] = T[kc * 16 + j][d];
  u16t* dst = vt + ((size_t)blockIdx.x * 64 + d) * 1024 + kt + kc * 16;
  *(uint4*)dst = o.u[0];
  *(uint4*)(dst + 8) = o.u[1];
}

// ---------- flash attention: block-shared LDS staging + 2-phase pipeline ----------
__global__ __launch_bounds__(256, 3) void attn_kernel(const u16t* __restrict__ qkv,
                                                      const u16t* __restrict__ vt,
                                                      u16t* __restrict__ ctx) {
  __shared__ __align__(16) u16t Ks[2][64 * 64];
  __shared__ __align__(16) u16t Vs[2][64 * 64];
  __shared__ __align__(16) u16t Plds[4][32 * 72];
  int tid = threadIdx.x;
  int wave = tid >> 6, lane = tid & 63;
  int q = lane & 15, g = lane >> 4;

  int bid = blockIdx.x;
  int xcd = bid & 7, j = bid >> 3;
  int head = xcd + 8 * (j >> 3);
  int qt = (j & 7) * 128 + wave * 32;
  int b = head / 12, h = head % 12;

  const u16t* base = qkv + (size_t)b * 1024 * 2304 + h * 64;
  const u16t* kbase = base + 768;
  const u16t* vtb = vt + (size_t)head * 64 * 1024;

  short8 qf[2][2];
#pragma unroll
  for (int hf = 0; hf < 2; hf++)
#pragma unroll
    for (int hh = 0; hh < 2; hh++)
      qf[hf][hh] = *(const short8*)(base + (size_t)(qt + hf * 16 + q) * 2304 + hh * 32 + g * 8);

  int lr = lane >> 3, lc = lane & 7;
  const u16t* ksrc = kbase + (size_t)lr * 2304 + (size_t)((lc ^ lr) * 8);
  const u16t* vsrc = vtb + (size_t)lr * 1024 + (size_t)((lc ^ lr) * 8);
  int c0 = wave * 2, c1 = wave * 2 + 1;

  auto stage = [&](int kt, int buf) {
    gload_lds16(ksrc + (size_t)(kt + c0 * 8) * 2304, (void*)(Ks[buf] + c0 * 512));
    gload_lds16(ksrc + (size_t)(kt + c1 * 8) * 2304, (void*)(Ks[buf] + c1 * 512));
    gload_lds16(vsrc + (size_t)(c0 * 8) * 1024 + kt, (void*)(Vs[buf] + c0 * 512));
    gload_lds16(vsrc + (size_t)(c1 * 8) * 1024 + kt, (void*)(Vs[buf] + c1 * 512));
  };

  float mA = -1e30f, mB = -1e30f, lA = 0.f, lB = 0.f;
  f32x4 oA[4] = {}, oB[4] = {};
  u16t* Pw = Plds[wave];

  stage(0, 0);
  __syncthreads();

  for (int t = 0; t < 16; ++t) {
    int buf = t & 1;
    if (t < 15) stage((t + 1) * 64, buf ^ 1);

    const u16t* Kb = Ks[buf];
    const u16t* Vb = Vs[buf];

    f32x4 sA[4] = {}, sB[4] = {};
    __builtin_amdgcn_s_setprio(1);
#pragma unroll
    for (int n = 0; n < 4; n++) {
      int row = n * 16 + q;
      short8 k0 = *(const short8*)(Kb + row * 64 + ((g ^ (q & 7)) * 8));
      short8 k1 = *(const short8*)(Kb + row * 64 + (((4 + g) ^ (q & 7)) * 8));
      sA[n] = __builtin_amdgcn_mfma_f32_16x16x32_bf16(k0, qf[0][0], sA[n], 0, 0, 0);
      sA[n] = __builtin_amdgcn_mfma_f32_16x16x32_bf16(k1, qf[0][1], sA[n], 0, 0, 0);
      sB[n] = __builtin_amdgcn_mfma_f32_16x16x32_bf16(k0, qf[1][0], sB[n], 0, 0, 0);
      sB[n] = __builtin_amdgcn_mfma_f32_16x16x32_bf16(k1, qf[1][1], sB[n], 0, 0, 0);
    }
    __builtin_amdgcn_s_setprio(0);

    float alphaA, alphaB;
    {
      float t0 = fmaxf(fmaxf(sA[0][0], sA[0][1]), fmaxf(sA[0][2], sA[0][3]));
      float t1 = fmaxf(fmaxf(sA[1][0], sA[1][1]), fmaxf(sA[1][2], sA[1][3]));
      float t2 = fmaxf(fmaxf(sA[2][0], sA[2][1]), fmaxf(sA[2][2], sA[2][3]));
      float t3 = fmaxf(fmaxf(sA[3][0], sA[3][1]), fmaxf(sA[3][2], sA[3][3]));
      float tm = fmaxf(fmaxf(t0, t1), fmaxf(t2, t3));
      tm = fmaxf(tm, __shfl_xor(tm, 16, 64));
      tm = fmaxf(tm, __shfl_xor(tm, 32, 64));
      float mnew = fmaxf(mA, tm);
      alphaA = __expf((mA - mnew) * 0.125f);
      mA = mnew;
#pragma unroll
      for (int n = 0; n < 4; n++)
#pragma unroll
        for (int i = 0; i < 4; i++) sA[n][i] = __expf((sA[n][i] - mnew) * 0.125f);
      float r0 = (sA[0][0] + sA[0][1]) + (sA[0][2] + sA[0][3]);
      float r1 = (sA[1][0] + sA[1][1]) + (sA[1][2] + sA[1][3]);
      float r2 = (sA[2][0] + sA[2][1]) + (sA[2][2] + sA[2][3]);
      float r3 = (sA[3][0] + sA[3][1]) + (sA[3][2] + sA[3][3]);
      float rs = (r0 + r1) + (r2 + r3);
      rs += __shfl_xor(rs, 16, 64);
      rs += __shfl_xor(rs, 32, 64);
      lA = lA * alphaA + rs;
#pragma unroll
      for (int n = 0; n < 4; n++) {
        uint32_t w0 = cvtpk(sA[n][0], sA[n][1]);
        uint32_t w1 = cvtpk(sA[n][2], sA[n][3]);
        *(uint2*)(Pw + q * 72 + n * 16 + g * 4) = make_uint2(w0, w1);
      }
    }
    {
      float t0 = fmaxf(fmaxf(sB[0][0], sB[0][1]), fmaxf(sB[0][2], sB[0][3]));
      float t1 = fmaxf(fmaxf(sB[1][0], sB[1][1]), fmaxf(sB[1][2], sB[1][3]));
      float t2 = fmaxf(fmaxf(sB[2][0], sB[2][1]), fmaxf(sB[2][2], sB[2][3]));
      float t3 = fmaxf(fmaxf(sB[3][0], sB[3][1]), fmaxf(sB[3][2], sB[3][3]));
      float tm = fmaxf(fmaxf(t0, t1), fmaxf(t2, t3));
      tm = fmaxf(tm, __shfl_xor(tm, 16, 64));
      tm = fmaxf(tm, __shfl_xor(tm, 32, 64));
      float mnew = fmaxf(mB, tm);
      alphaB = __expf((mB - mnew) * 0.125f);
      mB = mnew;
#pragma unroll
      for (int n = 0; n < 4; n++)
#pragma unroll
        for (int i = 0; i < 4; i++) sB[n][i] = __expf((sB[n][i] - mnew) * 0.125f);
      float r0 = (sB[0][0] + sB[0][1]) + (sB[0][2] + sB[0][3]);
      float r1 = (sB[1][0] + sB[1][1]) + (sB[1][2] + sB[1][3]);
      float r2 = (sB[2][0] + sB[2][1]) + (sB[2][2] + sB[2][3]);
      float r3 = (sB[3][0] + sB[3][1]) + (sB[3][2] + sB[3][3]);
      float rs = (r0 + r1) + (r2 + r3);
      rs += __shfl_xor(rs, 16, 64);
      rs += __shfl_xor(rs, 32, 64);
      lB = lB * alphaB + rs;
#pragma unroll
      for (int n = 0; n < 4; n++) {
        uint32_t w0 = cvtpk(sB[n][0], sB[n][1]);
        uint32_t w1 = cvtpk(sB[n][2], sB[n][3]);
        *(uint2*)(Pw + (16 + q) * 72 + n * 16 + g * 4) = make_uint2(w0, w1);
      }
    }

#pragma unroll
    for (int n = 0; n < 4; n++)
#pragma unroll
      for (int i = 0; i < 4; i++) {
        oA[n][i] *= alphaA;
        oB[n][i] *= alphaB;
      }

    short8 pA[2], pB[2];
#pragma unroll
    for (int hh = 0; hh < 2; hh++) {
      pA[hh] = *(const short8*)(Pw + q * 72 + hh * 32 + g * 8);
      pB[hh] = *(const short8*)(Pw + (16 + q) * 72 + hh * 32 + g * 8);
    }
    __builtin_amdgcn_s_setprio(1);
#pragma unroll
    for (int n = 0; n < 4; n++) {
      int row = n * 16 + q;
      short8 v0 = *(const short8*)(Vb + row * 64 + ((g ^ (q & 7)) * 8));
      short8 v1 = *(const short8*)(Vb + row * 64 + (((4 + g) ^ (q & 7)) * 8));
      oA[n] = __builtin_amdgcn_mfma_f32_16x16x32_bf16(v0, pA[0], oA[n], 0, 0, 0);
      oA[n] = __builtin_amdgcn_mfma_f32_16x16x32_bf16(v1, pA[1], oA[n], 0, 0, 0);
      oB[n] = __builtin_amdgcn_mfma_f32_16x16x32_bf16(v0, pB[0], oB[n], 0, 0, 0);
      oB[n] = __builtin_amdgcn_mfma_f32_16x16x32_bf16(v1, pB[1], oB[n], 0, 0, 0);
    }
    __builtin_amdgcn_s_setprio(0);

    __syncthreads();
  }

  float invA = 1.f / lA, invB = 1.f / lB;
  u16t* crowA = ctx + (size_t)(b * 1024 + qt + q) * 768 + h * 64;
  u16t* crowB = ctx + (size_t)(b * 1024 + qt + 16 + q) * 768 + h * 64;
#pragma unroll
  for (int n = 0; n < 4; n++) {
    uint32_t a0 = (uint32_t)f2bf(oA[n][0] * invA) | ((uint32_t)f2bf(oA[n][1] * invA) << 16);
    uint32_t a1 = (uint32_t)f2bf(oA[n][2] * invA) | ((uint32_t)f2bf(oA[n][3] * invA) << 16);
    *(uint32_t*)(crowA + n * 16 + g * 4) = a0;
    *(uint32_t*)(crowA + n * 16 + g * 4 + 2) = a1;
    uint32_t b0 = (uint32_t)f2bf(oB[n][0] * invB) | ((uint32_t)f2bf(oB[n][1] * invB) << 16);
    uint32_t b1 = (uint32_t)f2bf(oB[n][2] * invB) | ((uint32_t)f2bf(oB[n][3] * invB) << 16);
    *(uint32_t*)(crowB + n * 16 + g * 4) = b0;
    *(uint32_t*)(crowB + n * 16 + g * 4 + 2) = b1;
  }
}

// ---------- launch ----------
extern "C" void kernel_launch(void* const* d_in, const int* in_sizes, int n_in,
                              void* d_out, int out_size, void* d_ws, size_t ws_size,
                              hipStream_t stream) {
  const float* x      = (const float*)d_in[0];
  const float* ln1_g  = (const float*)d_in[1];
  const float* ln1_b  = (const float*)d_in[2];
  const float* qkv_w  = (const float*)d_in[3];
  const float* proj_w = (const float*)d_in[4];
  const float* proj_b = (const float*)d_in[5];
  const float* ln2_g  = (const float*)d_in[6];
  const float* ln2_b  = (const float*)d_in[7];
  const float* fc1_w  = (const float*)d_in[8];
  const float* fc1_b  = (const float*)d_in[9];
  const float* fc2_w  = (const float*)d_in[10];
  const float* fc2_b  = (const float*)d_in[11];

  char* ws = (char*)d_ws;
  u16t* h1   = (u16t*)(ws + 0);           // 8192x768 bf16 (ln1 out; REUSED as vt; then ln2 out)
  u16t* qkvb = (u16t*)(ws + 12582912);    // 8192x2304 bf16
  u16t* ctx  = (u16t*)(ws + 50331648);    // 8192x768 bf16
  float* x2  = (float*)(ws + 62914560);   // 8192x768 f32
  u16t* hid  = (u16t*)(ws + 88080384);    // 8192x3072 bf16
  u16t* wq   = (u16t*)(ws + 138412032);   // 2304x768 bf16
  u16t* wp   = (u16t*)(ws + 141950976);   // 768x768 bf16
  u16t* w1   = (u16t*)(ws + 143130624);   // 3072x768 bf16
  u16t* w2   = (u16t*)(ws + 147849216);   // 768x3072 bf16
  u16t* vtb  = h1;                        // 96x64x1024 bf16, lifetime-disjoint
  float* out = (float*)d_out;

  cvt_bf16_kernel<<<864, 256, 0, stream>>>(qkv_w, wq, 221184);
  cvt_bf16_kernel<<<288, 256, 0, stream>>>(proj_w, wp, 73728);
  cvt_bf16_kernel<<<1152, 256, 0, stream>>>(fc1_w, w1, 294912);
  cvt_bf16_kernel<<<1152, 256, 0, stream>>>(fc2_w, w2, 294912);

  ln_kernel<<<8192, 256, 0, stream>>>(x, ln1_g, ln1_b, h1);
  // qkv: 256x256 tile, grid (N/256=9, M/256=32)
  gemm256<0, 256><<<dim3(9, 32), 512, 0, stream>>>(h1, wq, qkvb, nullptr, nullptr, 2304, 768);
  vtrans_kernel<<<dim3(96, 16), 256, 0, stream>>>(qkvb, vtb);
  attn_kernel<<<768, 256, 0, stream>>>(qkvb, vtb, ctx);
  // proj: 256x128 tile, grid (6, 32)
  gemm256<1, 128><<<dim3(6, 32), 512, 0, stream>>>(ctx, wp, x2, proj_b, x, 768, 768);
  ln_kernel<<<8192, 256, 0, stream>>>(x2, ln2_g, ln2_b, h1);
  // fc1: 256x256 tile, grid (12, 32)
  gemm256<2, 256><<<dim3(12, 32), 512, 0, stream>>>(h1, w1, hid, fc1_b, nullptr, 3072, 768);
  // fc2: 256x256 tile, grid (3, 32), K=3072
  gemm256<1, 256><<<dim3(3, 32), 512, 0, stream>>>(hid, w2, out, fc2_b, x2, 768, 3072);
}

// Round 12
// 313.752 us; speedup vs baseline: 1.5560x; 1.3401x over previous
//
#include <hip/hip_runtime.h>
#include <cstdint>

typedef __attribute__((ext_vector_type(8))) short short8;
typedef __attribute__((ext_vector_type(4))) float f32x4;
typedef unsigned short u16t;

// ---------- helpers ----------
__device__ __forceinline__ u16t f2bf(float f) {
  uint32_t u = __float_as_uint(f);
  u += 0x7fffu + ((u >> 16) & 1u);   // RNE
  return (u16t)(u >> 16);
}

__device__ __forceinline__ uint32_t cvtpk(float lo, float hi) {
  uint32_t r;
  asm("v_cvt_pk_bf16_f32 %0, %1, %2" : "=v"(r) : "v"(lo), "v"(hi));
  return r;
}

__device__ __forceinline__ void gload_lds16(const void* g, void* l) {
  __builtin_amdgcn_global_load_lds(
      (const __attribute__((address_space(1))) void*)g,
      (__attribute__((address_space(3))) void*)l, 16, 0, 0);
}

__device__ __forceinline__ float gelu_exact(float v) {
  return 0.5f * v * (1.0f + erff(v * 0.70710678118f));
}

// ---------- fused f32 -> bf16 convert of all 4 weights ----------
__global__ __launch_bounds__(256) void cvt_all_kernel(const float* __restrict__ qw,
                                                      const float* __restrict__ pw,
                                                      const float* __restrict__ f1w,
                                                      const float* __restrict__ f2w,
                                                      u16t* __restrict__ oq,
                                                      u16t* __restrict__ op,
                                                      u16t* __restrict__ o1,
                                                      u16t* __restrict__ o2) {
  int i = blockIdx.x * 256 + threadIdx.x;
  const float* src; u16t* dst; int j;
  if (i < 221184)      { src = qw;  dst = oq; j = i; }
  else if (i < 294912) { src = pw;  dst = op; j = i - 221184; }
  else if (i < 589824) { src = f1w; dst = o1; j = i - 294912; }
  else if (i < 884736) { src = f2w; dst = o2; j = i - 589824; }
  else return;
  const float4* p = (const float4*)src + (size_t)j * 2;
  float4 a = p[0], b = p[1];
  union { short8 v; u16t e[8]; } r;
  r.e[0] = f2bf(a.x); r.e[1] = f2bf(a.y); r.e[2] = f2bf(a.z); r.e[3] = f2bf(a.w);
  r.e[4] = f2bf(b.x); r.e[5] = f2bf(b.y); r.e[6] = f2bf(b.z); r.e[7] = f2bf(b.w);
  *((short8*)dst + j) = r.v;
}

// ---------- LayerNorm (row = 768 f32) -> bf16 ----------
__global__ __launch_bounds__(256) void ln_kernel(const float* __restrict__ x,
                                                 const float* __restrict__ g,
                                                 const float* __restrict__ b,
                                                 u16t* __restrict__ out) {
  int row = blockIdx.x, tid = threadIdx.x;
  int wave = tid >> 6, lane = tid & 63;
  const float* xr = x + (size_t)row * 768;
  float v0 = xr[tid], v1 = xr[tid + 256], v2 = xr[tid + 512];
  float s = v0 + v1 + v2;
  float q = v0 * v0 + v1 * v1 + v2 * v2;
#pragma unroll
  for (int m = 32; m >= 1; m >>= 1) {
    s += __shfl_xor(s, m, 64);
    q += __shfl_xor(q, m, 64);
  }
  __shared__ float red[8];
  if (lane == 0) { red[wave] = s; red[4 + wave] = q; }
  __syncthreads();
  s = red[0] + red[1] + red[2] + red[3];
  q = red[4] + red[5] + red[6] + red[7];
  float mu = s * (1.0f / 768.0f);
  float var = q * (1.0f / 768.0f) - mu * mu;
  float rs = rsqrtf(var + 1e-5f);
  u16t* orow = out + (size_t)row * 768;
  orow[tid]       = f2bf((v0 - mu) * rs * g[tid]       + b[tid]);
  orow[tid + 256] = f2bf((v1 - mu) * rs * g[tid + 256] + b[tid + 256]);
  orow[tid + 512] = f2bf((v2 - mu) * rs * g[tid + 512] + b[tid + 512]);
}

// ---------- gemm5: 512 thr, tile 128x256, BK=64, single-buffer serial ----------
// R9 structure (refcheck-proven), natural 2-D grid (no swizzle — R9 lesson).
// 48KB LDS -> ~3 blocks/CU of TLP. Packed swapped-operand epilogue.
template <int EPI>
__global__ __launch_bounds__(512, 1) void gemm5(const u16t* __restrict__ A,
                                                const u16t* __restrict__ W,
                                                void* __restrict__ Cout,
                                                const float* __restrict__ bias,
                                                const float* __restrict__ res,
                                                int N, int K) {
  __shared__ __align__(16) u16t As[128 * 64];
  __shared__ __align__(16) u16t Bs[256 * 64];
  int tid = threadIdx.x;
  int wid = tid >> 6, lane = tid & 63;
  int wr = wid >> 2, wc = wid & 3;
  int q = lane & 15, g = lane >> 4;
  int bm = blockIdx.y * 128;
  int bn = blockIdx.x * 256;

  f32x4 acc[4][4] = {};

  int lr = lane >> 3, lc = lane & 7;
  const u16t* Abase = A + (size_t)(bm + lr) * K + ((lc ^ lr) * 8);
  const u16t* Wbase = W + (size_t)(bn + lr) * K + ((lc ^ lr) * 8);

  int NT = K >> 6;
  for (int t = 0; t < NT; ++t) {
    int kt = t * 64;
#pragma unroll
    for (int i = 0; i < 2; i++) {
      int chunk = wid * 2 + i;
      gload_lds16(Abase + (size_t)(chunk * 8) * K + kt, (void*)(As + chunk * 512));
    }
#pragma unroll
    for (int i = 0; i < 4; i++) {
      int chunk = wid * 4 + i;
      gload_lds16(Wbase + (size_t)(chunk * 8) * K + kt, (void*)(Bs + chunk * 512));
    }
    __syncthreads();

    short8 af[4][2], bfr[4][2];
#pragma unroll
    for (int m = 0; m < 4; m++) {
      int row = wr * 64 + m * 16 + q;
#pragma unroll
      for (int s = 0; s < 2; s++)
        af[m][s] = *(const short8*)(As + row * 64 + (((s * 4 + g) ^ (row & 7)) * 8));
    }
#pragma unroll
    for (int n = 0; n < 4; n++) {
      int row = wc * 64 + n * 16 + q;
#pragma unroll
      for (int s = 0; s < 2; s++)
        bfr[n][s] = *(const short8*)(Bs + row * 64 + (((s * 4 + g) ^ (row & 7)) * 8));
    }
    __builtin_amdgcn_s_setprio(1);
#pragma unroll
    for (int m = 0; m < 4; m++)
#pragma unroll
      for (int n = 0; n < 4; n++) {
        acc[m][n] = __builtin_amdgcn_mfma_f32_16x16x32_bf16(bfr[n][0], af[m][0], acc[m][n], 0, 0, 0);
        acc[m][n] = __builtin_amdgcn_mfma_f32_16x16x32_bf16(bfr[n][1], af[m][1], acc[m][n], 0, 0, 0);
      }
    __builtin_amdgcn_s_setprio(0);
    __syncthreads();
  }

#pragma unroll
  for (int m = 0; m < 4; m++) {
    int r = bm + wr * 64 + m * 16 + q;
#pragma unroll
    for (int n = 0; n < 4; n++) {
      int c = bn + wc * 64 + n * 16 + g * 4;
      f32x4 v = acc[m][n];
      if constexpr (EPI == 0) {
        uint2 pk = make_uint2(cvtpk(v[0], v[1]), cvtpk(v[2], v[3]));
        *(uint2*)((u16t*)Cout + (size_t)r * N + c) = pk;
      } else if constexpr (EPI == 1) {
        const float4 bv = *(const float4*)(bias + c);
        const float4 rv = *(const float4*)(res + (size_t)r * N + c);
        float4 o;
        o.x = v[0] + bv.x + rv.x; o.y = v[1] + bv.y + rv.y;
        o.z = v[2] + bv.z + rv.z; o.w = v[3] + bv.w + rv.w;
        *(float4*)((float*)Cout + (size_t)r * N + c) = o;
      } else {
        const float4 bv = *(const float4*)(bias + c);
        uint2 pk = make_uint2(cvtpk(gelu_exact(v[0] + bv.x), gelu_exact(v[1] + bv.y)),
                              cvtpk(gelu_exact(v[2] + bv.z), gelu_exact(v[3] + bv.w)));
        *(uint2*)((u16t*)Cout + (size_t)r * N + c) = pk;
      }
    }
  }
}

// ---------- gemm4: 256 thr, tile 128x128, BK=64, single-buffer serial (R5) ----------
template <int EPI>
__global__ __launch_bounds__(256, 2) void gemm4(const u16t* __restrict__ A,
                                                const u16t* __restrict__ W,
                                                void* __restrict__ Cout,
                                                const float* __restrict__ bias,
                                                const float* __restrict__ res,
                                                int N, int K) {
  __shared__ __align__(16) u16t As[128 * 64];
  __shared__ __align__(16) u16t Bs[128 * 64];
  int tid = threadIdx.x;
  int wave = tid >> 6, lane = tid & 63;
  int wr = wave >> 1, wc = wave & 1;
  int q = lane & 15, g = lane >> 4;
  int bm = blockIdx.y * 128;
  int bn = blockIdx.x * 128;
  f32x4 acc[4][4] = {};

  int lr = lane >> 3, lc = lane & 7;
  const u16t* Abase = A + (size_t)(bm + lr) * K + ((lc ^ lr) * 8);
  const u16t* Wbase = W + (size_t)(bn + lr) * K + ((lc ^ lr) * 8);

  int NT = K >> 6;
  for (int t = 0; t < NT; ++t) {
    int kt = t * 64;
#pragma unroll
    for (int i = 0; i < 4; i++) {
      int chunk = wave * 4 + i;
      gload_lds16(Abase + (size_t)(chunk * 8) * K + kt, (void*)(As + chunk * 512));
      gload_lds16(Wbase + (size_t)(chunk * 8) * K + kt, (void*)(Bs + chunk * 512));
    }
    __syncthreads();

    short8 af[4][2], bfr[4][2];
#pragma unroll
    for (int m = 0; m < 4; m++) {
      int row = wr * 64 + m * 16 + q;
#pragma unroll
      for (int s = 0; s < 2; s++)
        af[m][s] = *(const short8*)(As + row * 64 + (((s * 4 + g) ^ (row & 7)) * 8));
    }
#pragma unroll
    for (int n = 0; n < 4; n++) {
      int row = wc * 64 + n * 16 + q;
#pragma unroll
      for (int s = 0; s < 2; s++)
        bfr[n][s] = *(const short8*)(Bs + row * 64 + (((s * 4 + g) ^ (row & 7)) * 8));
    }
    __builtin_amdgcn_s_setprio(1);
#pragma unroll
    for (int m = 0; m < 4; m++)
#pragma unroll
      for (int n = 0; n < 4; n++) {
        acc[m][n] = __builtin_amdgcn_mfma_f32_16x16x32_bf16(bfr[n][0], af[m][0], acc[m][n], 0, 0, 0);
        acc[m][n] = __builtin_amdgcn_mfma_f32_16x16x32_bf16(bfr[n][1], af[m][1], acc[m][n], 0, 0, 0);
      }
    __builtin_amdgcn_s_setprio(0);
    __syncthreads();
  }

#pragma unroll
  for (int m = 0; m < 4; m++) {
    int r = bm + wr * 64 + m * 16 + q;
#pragma unroll
    for (int n = 0; n < 4; n++) {
      int c = bn + wc * 64 + n * 16 + g * 4;
      f32x4 v = acc[m][n];
      if constexpr (EPI == 0) {
        uint2 pk = make_uint2(cvtpk(v[0], v[1]), cvtpk(v[2], v[3]));
        *(uint2*)((u16t*)Cout + (size_t)r * N + c) = pk;
      } else if constexpr (EPI == 1) {
        const float4 bv = *(const float4*)(bias + c);
        const float4 rv = *(const float4*)(res + (size_t)r * N + c);
        float4 o;
        o.x = v[0] + bv.x + rv.x; o.y = v[1] + bv.y + rv.y;
        o.z = v[2] + bv.z + rv.z; o.w = v[3] + bv.w + rv.w;
        *(float4*)((float*)Cout + (size_t)r * N + c) = o;
      } else {
        const float4 bv = *(const float4*)(bias + c);
        uint2 pk = make_uint2(cvtpk(gelu_exact(v[0] + bv.x), gelu_exact(v[1] + bv.y)),
                              cvtpk(gelu_exact(v[2] + bv.z), gelu_exact(v[3] + bv.w)));
        *(uint2*)((u16t*)Cout + (size_t)r * N + c) = pk;
      }
    }
  }
}

// ---------- V transpose: qkvb V-part -> vt[head][64][1024] ----------
__global__ __launch_bounds__(256) void vtrans_kernel(const u16t* __restrict__ qkv,
                                                     u16t* __restrict__ vt) {
  __shared__ u16t T[64][66];
  int h = blockIdx.x % 12, bb = blockIdx.x / 12, kt = blockIdx.y * 64;
  int t = threadIdx.x;
  int r = t >> 2, dc = t & 3;
  const u16t* src = qkv + (size_t)(bb * 1024 + kt + r) * 2304 + 1536 + h * 64 + dc * 16;
  union { uint4 u[2]; u16t e[16]; uint32_t w[8]; } buf;
  buf.u[0] = *(const uint4*)src;
  buf.u[1] = *(const uint4*)(src + 8);
#pragma unroll
  for (int j = 0; j < 8; j++)
    *(uint32_t*)&T[r][dc * 16 + 2 * j] = buf.w[j];
  __syncthreads();
  int d = t >> 2, kc = t & 3;
  union { uint4 u[2]; u16t e[16]; } o;
#pragma unroll
  for (int j = 0; j < 16; j++) o.e[j] = T[kc * 16 + j][d];
  u16t* dst = vt + ((size_t)blockIdx.x * 64 + d) * 1024 + kt + kc * 16;
  *(uint4*)dst = o.u[0];
  *(uint4*)(dst + 8) = o.u[1];
}

// ---------- flash attention: block-shared LDS staging + 2-phase pipeline ----------
__global__ __launch_bounds__(256, 3) void attn_kernel(const u16t* __restrict__ qkv,
                                                      const u16t* __restrict__ vt,
                                                      u16t* __restrict__ ctx) {
  __shared__ __align__(16) u16t Ks[2][64 * 64];
  __shared__ __align__(16) u16t Vs[2][64 * 64];
  __shared__ __align__(16) u16t Plds[4][32 * 72];
  int tid = threadIdx.x;
  int wave = tid >> 6, lane = tid & 63;
  int q = lane & 15, g = lane >> 4;

  int bid = blockIdx.x;
  int xcd = bid & 7, j = bid >> 3;
  int head = xcd + 8 * (j >> 3);
  int qt = (j & 7) * 128 + wave * 32;
  int b = head / 12, h = head % 12;

  const u16t* base = qkv + (size_t)b * 1024 * 2304 + h * 64;
  const u16t* kbase = base + 768;
  const u16t* vtb = vt + (size_t)head * 64 * 1024;

  short8 qf[2][2];
#pragma unroll
  for (int hf = 0; hf < 2; hf++)
#pragma unroll
    for (int hh = 0; hh < 2; hh++)
      qf[hf][hh] = *(const short8*)(base + (size_t)(qt + hf * 16 + q) * 2304 + hh * 32 + g * 8);

  int lr = lane >> 3, lc = lane & 7;
  const u16t* ksrc = kbase + (size_t)lr * 2304 + (size_t)((lc ^ lr) * 8);
  const u16t* vsrc = vtb + (size_t)lr * 1024 + (size_t)((lc ^ lr) * 8);
  int c0 = wave * 2, c1 = wave * 2 + 1;

  auto stage = [&](int kt, int buf) {
    gload_lds16(ksrc + (size_t)(kt + c0 * 8) * 2304, (void*)(Ks[buf] + c0 * 512));
    gload_lds16(ksrc + (size_t)(kt + c1 * 8) * 2304, (void*)(Ks[buf] + c1 * 512));
    gload_lds16(vsrc + (size_t)(c0 * 8) * 1024 + kt, (void*)(Vs[buf] + c0 * 512));
    gload_lds16(vsrc + (size_t)(c1 * 8) * 1024 + kt, (void*)(Vs[buf] + c1 * 512));
  };

  float mA = -1e30f, mB = -1e30f, lA = 0.f, lB = 0.f;
  f32x4 oA[4] = {}, oB[4] = {};
  u16t* Pw = Plds[wave];

  stage(0, 0);
  __syncthreads();

  for (int t = 0; t < 16; ++t) {
    int buf = t & 1;
    if (t < 15) stage((t + 1) * 64, buf ^ 1);

    const u16t* Kb = Ks[buf];
    const u16t* Vb = Vs[buf];

    f32x4 sA[4] = {}, sB[4] = {};
    __builtin_amdgcn_s_setprio(1);
#pragma unroll
    for (int n = 0; n < 4; n++) {
      int row = n * 16 + q;
      short8 k0 = *(const short8*)(Kb + row * 64 + ((g ^ (q & 7)) * 8));
      short8 k1 = *(const short8*)(Kb + row * 64 + (((4 + g) ^ (q & 7)) * 8));
      sA[n] = __builtin_amdgcn_mfma_f32_16x16x32_bf16(k0, qf[0][0], sA[n], 0, 0, 0);
      sA[n] = __builtin_amdgcn_mfma_f32_16x16x32_bf16(k1, qf[0][1], sA[n], 0, 0, 0);
      sB[n] = __builtin_amdgcn_mfma_f32_16x16x32_bf16(k0, qf[1][0], sB[n], 0, 0, 0);
      sB[n] = __builtin_amdgcn_mfma_f32_16x16x32_bf16(k1, qf[1][1], sB[n], 0, 0, 0);
    }
    __builtin_amdgcn_s_setprio(0);

    float alphaA, alphaB;
    {
      float t0 = fmaxf(fmaxf(sA[0][0], sA[0][1]), fmaxf(sA[0][2], sA[0][3]));
      float t1 = fmaxf(fmaxf(sA[1][0], sA[1][1]), fmaxf(sA[1][2], sA[1][3]));
      float t2 = fmaxf(fmaxf(sA[2][0], sA[2][1]), fmaxf(sA[2][2], sA[2][3]));
      float t3 = fmaxf(fmaxf(sA[3][0], sA[3][1]), fmaxf(sA[3][2], sA[3][3]));
      float tm = fmaxf(fmaxf(t0, t1), fmaxf(t2, t3));
      tm = fmaxf(tm, __shfl_xor(tm, 16, 64));
      tm = fmaxf(tm, __shfl_xor(tm, 32, 64));
      float mnew = fmaxf(mA, tm);
      alphaA = __expf((mA - mnew) * 0.125f);
      mA = mnew;
#pragma unroll
      for (int n = 0; n < 4; n++)
#pragma unroll
        for (int i = 0; i < 4; i++) sA[n][i] = __expf((sA[n][i] - mnew) * 0.125f);
      float r0 = (sA[0][0] + sA[0][1]) + (sA[0][2] + sA[0][3]);
      float r1 = (sA[1][0] + sA[1][1]) + (sA[1][2] + sA[1][3]);
      float r2 = (sA[2][0] + sA[2][1]) + (sA[2][2] + sA[2][3]);
      float r3 = (sA[3][0] + sA[3][1]) + (sA[3][2] + sA[3][3]);
      float rs = (r0 + r1) + (r2 + r3);
      rs += __shfl_xor(rs, 16, 64);
      rs += __shfl_xor(rs, 32, 64);
      lA = lA * alphaA + rs;
#pragma unroll
      for (int n = 0; n < 4; n++) {
        uint32_t w0 = cvtpk(sA[n][0], sA[n][1]);
        uint32_t w1 = cvtpk(sA[n][2], sA[n][3]);
        *(uint2*)(Pw + q * 72 + n * 16 + g * 4) = make_uint2(w0, w1);
      }
    }
    {
      float t0 = fmaxf(fmaxf(sB[0][0], sB[0][1]), fmaxf(sB[0][2], sB[0][3]));
      float t1 = fmaxf(fmaxf(sB[1][0], sB[1][1]), fmaxf(sB[1][2], sB[1][3]));
      float t2 = fmaxf(fmaxf(sB[2][0], sB[2][1]), fmaxf(sB[2][2], sB[2][3]));
      float t3 = fmaxf(fmaxf(sB[3][0], sB[3][1]), fmaxf(sB[3][2], sB[3][3]));
      float tm = fmaxf(fmaxf(t0, t1), fmaxf(t2, t3));
      tm = fmaxf(tm, __shfl_xor(tm, 16, 64));
      tm = fmaxf(tm, __shfl_xor(tm, 32, 64));
      float mnew = fmaxf(mB, tm);
      alphaB = __expf((mB - mnew) * 0.125f);
      mB = mnew;
#pragma unroll
      for (int n = 0; n < 4; n++)
#pragma unroll
        for (int i = 0; i < 4; i++) sB[n][i] = __expf((sB[n][i] - mnew) * 0.125f);
      float r0 = (sB[0][0] + sB[0][1]) + (sB[0][2] + sB[0][3]);
      float r1 = (sB[1][0] + sB[1][1]) + (sB[1][2] + sB[1][3]);
      float r2 = (sB[2][0] + sB[2][1]) + (sB[2][2] + sB[2][3]);
      float r3 = (sB[3][0] + sB[3][1]) + (sB[3][2] + sB[3][3]);
      float rs = (r0 + r1) + (r2 + r3);
      rs += __shfl_xor(rs, 16, 64);
      rs += __shfl_xor(rs, 32, 64);
      lB = lB * alphaB + rs;
#pragma unroll
      for (int n = 0; n < 4; n++) {
        uint32_t w0 = cvtpk(sB[n][0], sB[n][1]);
        uint32_t w1 = cvtpk(sB[n][2], sB[n][3]);
        *(uint2*)(Pw + (16 + q) * 72 + n * 16 + g * 4) = make_uint2(w0, w1);
      }
    }

#pragma unroll
    for (int n = 0; n < 4; n++)
#pragma unroll
      for (int i = 0; i < 4; i++) {
        oA[n][i] *= alphaA;
        oB[n][i] *= alphaB;
      }

    short8 pA[2], pB[2];
#pragma unroll
    for (int hh = 0; hh < 2; hh++) {
      pA[hh] = *(const short8*)(Pw + q * 72 + hh * 32 + g * 8);
      pB[hh] = *(const short8*)(Pw + (16 + q) * 72 + hh * 32 + g * 8);
    }
    __builtin_amdgcn_s_setprio(1);
#pragma unroll
    for (int n = 0; n < 4; n++) {
      int row = n * 16 + q;
      short8 v0 = *(const short8*)(Vb + row * 64 + ((g ^ (q & 7)) * 8));
      short8 v1 = *(const short8*)(Vb + row * 64 + (((4 + g) ^ (q & 7)) * 8));
      oA[n] = __builtin_amdgcn_mfma_f32_16x16x32_bf16(v0, pA[0], oA[n], 0, 0, 0);
      oA[n] = __builtin_amdgcn_mfma_f32_16x16x32_bf16(v1, pA[1], oA[n], 0, 0, 0);
      oB[n] = __builtin_amdgcn_mfma_f32_16x16x32_bf16(v0, pB[0], oB[n], 0, 0, 0);
      oB[n] = __builtin_amdgcn_mfma_f32_16x16x32_bf16(v1, pB[1], oB[n], 0, 0, 0);
    }
    __builtin_amdgcn_s_setprio(0);

    __syncthreads();
  }

  float invA = 1.f / lA, invB = 1.f / lB;
  u16t* crowA = ctx + (size_t)(b * 1024 + qt + q) * 768 + h * 64;
  u16t* crowB = ctx + (size_t)(b * 1024 + qt + 16 + q) * 768 + h * 64;
#pragma unroll
  for (int n = 0; n < 4; n++) {
    uint32_t a0 = (uint32_t)f2bf(oA[n][0] * invA) | ((uint32_t)f2bf(oA[n][1] * invA) << 16);
    uint32_t a1 = (uint32_t)f2bf(oA[n][2] * invA) | ((uint32_t)f2bf(oA[n][3] * invA) << 16);
    *(uint32_t*)(crowA + n * 16 + g * 4) = a0;
    *(uint32_t*)(crowA + n * 16 + g * 4 + 2) = a1;
    uint32_t b0 = (uint32_t)f2bf(oB[n][0] * invB) | ((uint32_t)f2bf(oB[n][1] * invB) << 16);
    uint32_t b1 = (uint32_t)f2bf(oB[n][2] * invB) | ((uint32_t)f2bf(oB[n][3] * invB) << 16);
    *(uint32_t*)(crowB + n * 16 + g * 4) = b0;
    *(uint32_t*)(crowB + n * 16 + g * 4 + 2) = b1;
  }
}

// ---------- launch ----------
extern "C" void kernel_launch(void* const* d_in, const int* in_sizes, int n_in,
                              void* d_out, int out_size, void* d_ws, size_t ws_size,
                              hipStream_t stream) {
  const float* x      = (const float*)d_in[0];
  const float* ln1_g  = (const float*)d_in[1];
  const float* ln1_b  = (const float*)d_in[2];
  const float* qkv_w  = (const float*)d_in[3];
  const float* proj_w = (const float*)d_in[4];
  const float* proj_b = (const float*)d_in[5];
  const float* ln2_g  = (const float*)d_in[6];
  const float* ln2_b  = (const float*)d_in[7];
  const float* fc1_w  = (const float*)d_in[8];
  const float* fc1_b  = (const float*)d_in[9];
  const float* fc2_w  = (const float*)d_in[10];
  const float* fc2_b  = (const float*)d_in[11];

  char* ws = (char*)d_ws;
  u16t* h1   = (u16t*)(ws + 0);           // 8192x768 bf16 (ln1 out; REUSED as vt; then ln2 out)
  u16t* qkvb = (u16t*)(ws + 12582912);    // 8192x2304 bf16
  u16t* ctx  = (u16t*)(ws + 50331648);    // 8192x768 bf16
  float* x2  = (float*)(ws + 62914560);   // 8192x768 f32
  u16t* hid  = (u16t*)(ws + 88080384);    // 8192x3072 bf16
  u16t* wq   = (u16t*)(ws + 138412032);   // 2304x768 bf16
  u16t* wp   = (u16t*)(ws + 141950976);   // 768x768 bf16
  u16t* w1   = (u16t*)(ws + 143130624);   // 3072x768 bf16
  u16t* w2   = (u16t*)(ws + 147849216);   // 768x3072 bf16
  u16t* vtb  = h1;                        // 96x64x1024 bf16, lifetime-disjoint
  float* out = (float*)d_out;

  cvt_all_kernel<<<3456, 256, 0, stream>>>(qkv_w, proj_w, fc1_w, fc2_w, wq, wp, w1, w2);

  ln_kernel<<<8192, 256, 0, stream>>>(x, ln1_g, ln1_b, h1);
  // qkv: 128x256 tile, grid (2304/256=9, 8192/128=64)
  gemm5<0><<<dim3(9, 64), 512, 0, stream>>>(h1, wq, qkvb, nullptr, nullptr, 2304, 768);
  vtrans_kernel<<<dim3(96, 16), 256, 0, stream>>>(qkvb, vtb);
  attn_kernel<<<768, 256, 0, stream>>>(qkvb, vtb, ctx);
  // proj: 128x128 tile, grid (6, 64)
  gemm4<1><<<dim3(6, 64), 256, 0, stream>>>(ctx, wp, x2, proj_b, x, 768, 768);
  ln_kernel<<<8192, 256, 0, stream>>>(x2, ln2_g, ln2_b, h1);
  // fc1: 128x256 tile, grid (12, 64)
  gemm5<2><<<dim3(12, 64), 512, 0, stream>>>(h1, w1, hid, fc1_b, nullptr, 3072, 768);
  // fc2: 128x128 tile, grid (6, 64), K=3072
  gemm4<1><<<dim3(6, 64), 256, 0, stream>>>(hid, w2, out, fc2_b, x2, 768, 3072);
}

// Round 13
// 276.192 us; speedup vs baseline: 1.7676x; 1.1360x over previous
//
#include <hip/hip_runtime.h>
#include <cstdint>

typedef __attribute__((ext_vector_type(8))) short short8;
typedef __attribute__((ext_vector_type(4))) float f32x4;
typedef unsigned short u16t;

// ---------- helpers ----------
__device__ __forceinline__ u16t f2bf(float f) {
  uint32_t u = __float_as_uint(f);
  u += 0x7fffu + ((u >> 16) & 1u);   // RNE
  return (u16t)(u >> 16);
}

__device__ __forceinline__ uint32_t cvtpk(float lo, float hi) {
  uint32_t r;
  asm("v_cvt_pk_bf16_f32 %0, %1, %2" : "=v"(r) : "v"(lo), "v"(hi));
  return r;
}

__device__ __forceinline__ void gload_lds16(const void* g, void* l) {
  __builtin_amdgcn_global_load_lds(
      (const __attribute__((address_space(1))) void*)g,
      (__attribute__((address_space(3))) void*)l, 16, 0, 0);
}

__device__ __forceinline__ float gelu_exact(float v) {
  return 0.5f * v * (1.0f + erff(v * 0.70710678118f));
}

// ---------- fused f32 -> bf16 convert of all 4 weights ----------
__global__ __launch_bounds__(256) void cvt_all_kernel(const float* __restrict__ qw,
                                                      const float* __restrict__ pw,
                                                      const float* __restrict__ f1w,
                                                      const float* __restrict__ f2w,
                                                      u16t* __restrict__ oq,
                                                      u16t* __restrict__ op,
                                                      u16t* __restrict__ o1,
                                                      u16t* __restrict__ o2) {
  int i = blockIdx.x * 256 + threadIdx.x;
  const float* src; u16t* dst; int j;
  if (i < 221184)      { src = qw;  dst = oq; j = i; }
  else if (i < 294912) { src = pw;  dst = op; j = i - 221184; }
  else if (i < 589824) { src = f1w; dst = o1; j = i - 294912; }
  else if (i < 884736) { src = f2w; dst = o2; j = i - 589824; }
  else return;
  const float4* p = (const float4*)src + (size_t)j * 2;
  float4 a = p[0], b = p[1];
  union { short8 v; u16t e[8]; } r;
  r.e[0] = f2bf(a.x); r.e[1] = f2bf(a.y); r.e[2] = f2bf(a.z); r.e[3] = f2bf(a.w);
  r.e[4] = f2bf(b.x); r.e[5] = f2bf(b.y); r.e[6] = f2bf(b.z); r.e[7] = f2bf(b.w);
  *((short8*)dst + j) = r.v;
}

// ---------- LayerNorm (row = 768 f32) -> bf16 ----------
__global__ __launch_bounds__(256) void ln_kernel(const float* __restrict__ x,
                                                 const float* __restrict__ g,
                                                 const float* __restrict__ b,
                                                 u16t* __restrict__ out) {
  int row = blockIdx.x, tid = threadIdx.x;
  int wave = tid >> 6, lane = tid & 63;
  const float* xr = x + (size_t)row * 768;
  float v0 = xr[tid], v1 = xr[tid + 256], v2 = xr[tid + 512];
  float s = v0 + v1 + v2;
  float q = v0 * v0 + v1 * v1 + v2 * v2;
#pragma unroll
  for (int m = 32; m >= 1; m >>= 1) {
    s += __shfl_xor(s, m, 64);
    q += __shfl_xor(q, m, 64);
  }
  __shared__ float red[8];
  if (lane == 0) { red[wave] = s; red[4 + wave] = q; }
  __syncthreads();
  s = red[0] + red[1] + red[2] + red[3];
  q = red[4] + red[5] + red[6] + red[7];
  float mu = s * (1.0f / 768.0f);
  float var = q * (1.0f / 768.0f) - mu * mu;
  float rs = rsqrtf(var + 1e-5f);
  u16t* orow = out + (size_t)row * 768;
  orow[tid]       = f2bf((v0 - mu) * rs * g[tid]       + b[tid]);
  orow[tid + 256] = f2bf((v1 - mu) * rs * g[tid + 256] + b[tid + 256]);
  orow[tid + 512] = f2bf((v2 - mu) * rs * g[tid + 512] + b[tid + 512]);
}

// ---------- gemm_bt: R5 structure + XCD-pinned row-fast tile remap ----------
// C[M=8192,N] = A @ W^T, bf16 in / fp32 acc, tile 128x128, BK=64, 256 thr,
// single-buffer LDS, serial 2-barrier loop (measured-best structure).
// 1-D grid, bijective remap: xcd = b&7 owns contiguous tile range; within an
// XCD tiles go row-fast (col slow) -> W panel L2-resident + A row-panel L2 reuse.
// EPI 0: bf16; EPI 1: f32 acc+bias+res; EPI 2: bf16 gelu(acc+bias)
template <int EPI>
__global__ __launch_bounds__(256, 2) void gemm_bt(const u16t* __restrict__ A,
                                                  const u16t* __restrict__ W,
                                                  void* __restrict__ Cout,
                                                  const float* __restrict__ bias,
                                                  const float* __restrict__ res,
                                                  int N, int K) {
  __shared__ __align__(16) u16t As[128 * 64];
  __shared__ __align__(16) u16t Bs[128 * 64];
  int tid = threadIdx.x;
  int wave = tid >> 6, lane = tid & 63;
  int wr = wave >> 1, wc = wave & 1;
  int q = lane & 15, g = lane >> 4;

  // XCD-pinned remap (grid % 8 == 0 for all launches; nbm = 64)
  int G = gridDim.x;
  int b = blockIdx.x;
  int gt = (b & 7) * (G >> 3) + (b >> 3);
  int col = gt >> 6;          // slow: contiguous cols per XCD -> W L2-resident
  int row = gt & 63;          // fast: A row-panel reused across its col visits
  int bm = row * 128;
  int bn = col * 128;

  f32x4 acc[4][4] = {};

  int lr = lane >> 3, lc = lane & 7;
  const u16t* Abase = A + (size_t)(bm + lr) * K + ((lc ^ lr) * 8);
  const u16t* Wbase = W + (size_t)(bn + lr) * K + ((lc ^ lr) * 8);

  int NT = K >> 6;
  for (int t = 0; t < NT; ++t) {
    int kt = t * 64;
#pragma unroll
    for (int i = 0; i < 4; i++) {
      int chunk = wave * 4 + i;
      gload_lds16(Abase + (size_t)(chunk * 8) * K + kt, (void*)(As + chunk * 512));
      gload_lds16(Wbase + (size_t)(chunk * 8) * K + kt, (void*)(Bs + chunk * 512));
    }
    __syncthreads();

    short8 af[4][2], bfr[4][2];
#pragma unroll
    for (int m = 0; m < 4; m++) {
      int r = wr * 64 + m * 16 + q;
#pragma unroll
      for (int s = 0; s < 2; s++)
        af[m][s] = *(const short8*)(As + r * 64 + (((s * 4 + g) ^ (r & 7)) * 8));
    }
#pragma unroll
    for (int n = 0; n < 4; n++) {
      int r = wc * 64 + n * 16 + q;
#pragma unroll
      for (int s = 0; s < 2; s++)
        bfr[n][s] = *(const short8*)(Bs + r * 64 + (((s * 4 + g) ^ (r & 7)) * 8));
    }
    __builtin_amdgcn_s_setprio(1);
#pragma unroll
    for (int m = 0; m < 4; m++)
#pragma unroll
      for (int n = 0; n < 4; n++) {
        acc[m][n] = __builtin_amdgcn_mfma_f32_16x16x32_bf16(bfr[n][0], af[m][0], acc[m][n], 0, 0, 0);
        acc[m][n] = __builtin_amdgcn_mfma_f32_16x16x32_bf16(bfr[n][1], af[m][1], acc[m][n], 0, 0, 0);
      }
    __builtin_amdgcn_s_setprio(0);
    __syncthreads();
  }

  // epilogue: lane owns row (fixed), 4 consecutive cols -> packed stores
#pragma unroll
  for (int m = 0; m < 4; m++) {
    int r = bm + wr * 64 + m * 16 + q;
#pragma unroll
    for (int n = 0; n < 4; n++) {
      int c = bn + wc * 64 + n * 16 + g * 4;
      f32x4 v = acc[m][n];
      if constexpr (EPI == 0) {
        uint2 pk = make_uint2(cvtpk(v[0], v[1]), cvtpk(v[2], v[3]));
        *(uint2*)((u16t*)Cout + (size_t)r * N + c) = pk;
      } else if constexpr (EPI == 1) {
        const float4 bv = *(const float4*)(bias + c);
        const float4 rv = *(const float4*)(res + (size_t)r * N + c);
        float4 o;
        o.x = v[0] + bv.x + rv.x; o.y = v[1] + bv.y + rv.y;
        o.z = v[2] + bv.z + rv.z; o.w = v[3] + bv.w + rv.w;
        *(float4*)((float*)Cout + (size_t)r * N + c) = o;
      } else {
        const float4 bv = *(const float4*)(bias + c);
        uint2 pk = make_uint2(cvtpk(gelu_exact(v[0] + bv.x), gelu_exact(v[1] + bv.y)),
                              cvtpk(gelu_exact(v[2] + bv.z), gelu_exact(v[3] + bv.w)));
        *(uint2*)((u16t*)Cout + (size_t)r * N + c) = pk;
      }
    }
  }
}

// ---------- V transpose: qkvb V-part -> vt[head][64][1024] ----------
__global__ __launch_bounds__(256) void vtrans_kernel(const u16t* __restrict__ qkv,
                                                     u16t* __restrict__ vt) {
  __shared__ u16t T[64][66];
  int h = blockIdx.x % 12, bb = blockIdx.x / 12, kt = blockIdx.y * 64;
  int t = threadIdx.x;
  int r = t >> 2, dc = t & 3;
  const u16t* src = qkv + (size_t)(bb * 1024 + kt + r) * 2304 + 1536 + h * 64 + dc * 16;
  union { uint4 u[2]; u16t e[16]; uint32_t w[8]; } buf;
  buf.u[0] = *(const uint4*)src;
  buf.u[1] = *(const uint4*)(src + 8);
#pragma unroll
  for (int j = 0; j < 8; j++)
    *(uint32_t*)&T[r][dc * 16 + 2 * j] = buf.w[j];
  __syncthreads();
  int d = t >> 2, kc = t & 3;
  union { uint4 u[2]; u16t e[16]; } o;
#pragma unroll
  for (int j = 0; j < 16; j++) o.e[j] = T[kc * 16 + j][d];
  u16t* dst = vt + ((size_t)blockIdx.x * 64 + d) * 1024 + kt + kc * 16;
  *(uint4*)dst = o.u[0];
  *(uint4*)(dst + 8) = o.u[1];
}

// ---------- flash attention: block-shared LDS staging + 2-phase pipeline ----------
__global__ __launch_bounds__(256, 3) void attn_kernel(const u16t* __restrict__ qkv,
                                                      const u16t* __restrict__ vt,
                                                      u16t* __restrict__ ctx) {
  __shared__ __align__(16) u16t Ks[2][64 * 64];
  __shared__ __align__(16) u16t Vs[2][64 * 64];
  __shared__ __align__(16) u16t Plds[4][32 * 72];
  int tid = threadIdx.x;
  int wave = tid >> 6, lane = tid & 63;
  int q = lane & 15, g = lane >> 4;

  int bid = blockIdx.x;
  int xcd = bid & 7, j = bid >> 3;
  int head = xcd + 8 * (j >> 3);
  int qt = (j & 7) * 128 + wave * 32;
  int b = head / 12, h = head % 12;

  const u16t* base = qkv + (size_t)b * 1024 * 2304 + h * 64;
  const u16t* kbase = base + 768;
  const u16t* vtb = vt + (size_t)head * 64 * 1024;

  short8 qf[2][2];
#pragma unroll
  for (int hf = 0; hf < 2; hf++)
#pragma unroll
    for (int hh = 0; hh < 2; hh++)
      qf[hf][hh] = *(const short8*)(base + (size_t)(qt + hf * 16 + q) * 2304 + hh * 32 + g * 8);

  int lr = lane >> 3, lc = lane & 7;
  const u16t* ksrc = kbase + (size_t)lr * 2304 + (size_t)((lc ^ lr) * 8);
  const u16t* vsrc = vtb + (size_t)lr * 1024 + (size_t)((lc ^ lr) * 8);
  int c0 = wave * 2, c1 = wave * 2 + 1;

  auto stage = [&](int kt, int buf) {
    gload_lds16(ksrc + (size_t)(kt + c0 * 8) * 2304, (void*)(Ks[buf] + c0 * 512));
    gload_lds16(ksrc + (size_t)(kt + c1 * 8) * 2304, (void*)(Ks[buf] + c1 * 512));
    gload_lds16(vsrc + (size_t)(c0 * 8) * 1024 + kt, (void*)(Vs[buf] + c0 * 512));
    gload_lds16(vsrc + (size_t)(c1 * 8) * 1024 + kt, (void*)(Vs[buf] + c1 * 512));
  };

  float mA = -1e30f, mB = -1e30f, lA = 0.f, lB = 0.f;
  f32x4 oA[4] = {}, oB[4] = {};
  u16t* Pw = Plds[wave];

  stage(0, 0);
  __syncthreads();

  for (int t = 0; t < 16; ++t) {
    int buf = t & 1;
    if (t < 15) stage((t + 1) * 64, buf ^ 1);

    const u16t* Kb = Ks[buf];
    const u16t* Vb = Vs[buf];

    f32x4 sA[4] = {}, sB[4] = {};
    __builtin_amdgcn_s_setprio(1);
#pragma unroll
    for (int n = 0; n < 4; n++) {
      int row = n * 16 + q;
      short8 k0 = *(const short8*)(Kb + row * 64 + ((g ^ (q & 7)) * 8));
      short8 k1 = *(const short8*)(Kb + row * 64 + (((4 + g) ^ (q & 7)) * 8));
      sA[n] = __builtin_amdgcn_mfma_f32_16x16x32_bf16(k0, qf[0][0], sA[n], 0, 0, 0);
      sA[n] = __builtin_amdgcn_mfma_f32_16x16x32_bf16(k1, qf[0][1], sA[n], 0, 0, 0);
      sB[n] = __builtin_amdgcn_mfma_f32_16x16x32_bf16(k0, qf[1][0], sB[n], 0, 0, 0);
      sB[n] = __builtin_amdgcn_mfma_f32_16x16x32_bf16(k1, qf[1][1], sB[n], 0, 0, 0);
    }
    __builtin_amdgcn_s_setprio(0);

    float alphaA, alphaB;
    {
      float t0 = fmaxf(fmaxf(sA[0][0], sA[0][1]), fmaxf(sA[0][2], sA[0][3]));
      float t1 = fmaxf(fmaxf(sA[1][0], sA[1][1]), fmaxf(sA[1][2], sA[1][3]));
      float t2 = fmaxf(fmaxf(sA[2][0], sA[2][1]), fmaxf(sA[2][2], sA[2][3]));
      float t3 = fmaxf(fmaxf(sA[3][0], sA[3][1]), fmaxf(sA[3][2], sA[3][3]));
      float tm = fmaxf(fmaxf(t0, t1), fmaxf(t2, t3));
      tm = fmaxf(tm, __shfl_xor(tm, 16, 64));
      tm = fmaxf(tm, __shfl_xor(tm, 32, 64));
      float mnew = fmaxf(mA, tm);
      alphaA = __expf((mA - mnew) * 0.125f);
      mA = mnew;
#pragma unroll
      for (int n = 0; n < 4; n++)
#pragma unroll
        for (int i = 0; i < 4; i++) sA[n][i] = __expf((sA[n][i] - mnew) * 0.125f);
      float r0 = (sA[0][0] + sA[0][1]) + (sA[0][2] + sA[0][3]);
      float r1 = (sA[1][0] + sA[1][1]) + (sA[1][2] + sA[1][3]);
      float r2 = (sA[2][0] + sA[2][1]) + (sA[2][2] + sA[2][3]);
      float r3 = (sA[3][0] + sA[3][1]) + (sA[3][2] + sA[3][3]);
      float rs = (r0 + r1) + (r2 + r3);
      rs += __shfl_xor(rs, 16, 64);
      rs += __shfl_xor(rs, 32, 64);
      lA = lA * alphaA + rs;
#pragma unroll
      for (int n = 0; n < 4; n++) {
        uint32_t w0 = cvtpk(sA[n][0], sA[n][1]);
        uint32_t w1 = cvtpk(sA[n][2], sA[n][3]);
        *(uint2*)(Pw + q * 72 + n * 16 + g * 4) = make_uint2(w0, w1);
      }
    }
    {
      float t0 = fmaxf(fmaxf(sB[0][0], sB[0][1]), fmaxf(sB[0][2], sB[0][3]));
      float t1 = fmaxf(fmaxf(sB[1][0], sB[1][1]), fmaxf(sB[1][2], sB[1][3]));
      float t2 = fmaxf(fmaxf(sB[2][0], sB[2][1]), fmaxf(sB[2][2], sB[2][3]));
      float t3 = fmaxf(fmaxf(sB[3][0], sB[3][1]), fmaxf(sB[3][2], sB[3][3]));
      float tm = fmaxf(fmaxf(t0, t1), fmaxf(t2, t3));
      tm = fmaxf(tm, __shfl_xor(tm, 16, 64));
      tm = fmaxf(tm, __shfl_xor(tm, 32, 64));
      float mnew = fmaxf(mB, tm);
      alphaB = __expf((mB - mnew) * 0.125f);
      mB = mnew;
#pragma unroll
      for (int n = 0; n < 4; n++)
#pragma unroll
        for (int i = 0; i < 4; i++) sB[n][i] = __expf((sB[n][i] - mnew) * 0.125f);
      float r0 = (sB[0][0] + sB[0][1]) + (sB[0][2] + sB[0][3]);
      float r1 = (sB[1][0] + sB[1][1]) + (sB[1][2] + sB[1][3]);
      float r2 = (sB[2][0] + sB[2][1]) + (sB[2][2] + sB[2][3]);
      float r3 = (sB[3][0] + sB[3][1]) + (sB[3][2] + sB[3][3]);
      float rs = (r0 + r1) + (r2 + r3);
      rs += __shfl_xor(rs, 16, 64);
      rs += __shfl_xor(rs, 32, 64);
      lB = lB * alphaB + rs;
#pragma unroll
      for (int n = 0; n < 4; n++) {
        uint32_t w0 = cvtpk(sB[n][0], sB[n][1]);
        uint32_t w1 = cvtpk(sB[n][2], sB[n][3]);
        *(uint2*)(Pw + (16 + q) * 72 + n * 16 + g * 4) = make_uint2(w0, w1);
      }
    }

#pragma unroll
    for (int n = 0; n < 4; n++)
#pragma unroll
      for (int i = 0; i < 4; i++) {
        oA[n][i] *= alphaA;
        oB[n][i] *= alphaB;
      }

    short8 pA[2], pB[2];
#pragma unroll
    for (int hh = 0; hh < 2; hh++) {
      pA[hh] = *(const short8*)(Pw + q * 72 + hh * 32 + g * 8);
      pB[hh] = *(const short8*)(Pw + (16 + q) * 72 + hh * 32 + g * 8);
    }
    __builtin_amdgcn_s_setprio(1);
#pragma unroll
    for (int n = 0; n < 4; n++) {
      int row = n * 16 + q;
      short8 v0 = *(const short8*)(Vb + row * 64 + ((g ^ (q & 7)) * 8));
      short8 v1 = *(const short8*)(Vb + row * 64 + (((4 + g) ^ (q & 7)) * 8));
      oA[n] = __builtin_amdgcn_mfma_f32_16x16x32_bf16(v0, pA[0], oA[n], 0, 0, 0);
      oA[n] = __builtin_amdgcn_mfma_f32_16x16x32_bf16(v1, pA[1], oA[n], 0, 0, 0);
      oB[n] = __builtin_amdgcn_mfma_f32_16x16x32_bf16(v0, pB[0], oB[n], 0, 0, 0);
      oB[n] = __builtin_amdgcn_mfma_f32_16x16x32_bf16(v1, pB[1], oB[n], 0, 0, 0);
    }
    __builtin_amdgcn_s_setprio(0);

    __syncthreads();
  }

  float invA = 1.f / lA, invB = 1.f / lB;
  u16t* crowA = ctx + (size_t)(b * 1024 + qt + q) * 768 + h * 64;
  u16t* crowB = ctx + (size_t)(b * 1024 + qt + 16 + q) * 768 + h * 64;
#pragma unroll
  for (int n = 0; n < 4; n++) {
    uint32_t a0 = (uint32_t)f2bf(oA[n][0] * invA) | ((uint32_t)f2bf(oA[n][1] * invA) << 16);
    uint32_t a1 = (uint32_t)f2bf(oA[n][2] * invA) | ((uint32_t)f2bf(oA[n][3] * invA) << 16);
    *(uint32_t*)(crowA + n * 16 + g * 4) = a0;
    *(uint32_t*)(crowA + n * 16 + g * 4 + 2) = a1;
    uint32_t b0 = (uint32_t)f2bf(oB[n][0] * invB) | ((uint32_t)f2bf(oB[n][1] * invB) << 16);
    uint32_t b1 = (uint32_t)f2bf(oB[n][2] * invB) | ((uint32_t)f2bf(oB[n][3] * invB) << 16);
    *(uint32_t*)(crowB + n * 16 + g * 4) = b0;
    *(uint32_t*)(crowB + n * 16 + g * 4 + 2) = b1;
  }
}

// ---------- launch ----------
extern "C" void kernel_launch(void* const* d_in, const int* in_sizes, int n_in,
                              void* d_out, int out_size, void* d_ws, size_t ws_size,
                              hipStream_t stream) {
  const float* x      = (const float*)d_in[0];
  const float* ln1_g  = (const float*)d_in[1];
  const float* ln1_b  = (const float*)d_in[2];
  const float* qkv_w  = (const float*)d_in[3];
  const float* proj_w = (const float*)d_in[4];
  const float* proj_b = (const float*)d_in[5];
  const float* ln2_g  = (const float*)d_in[6];
  const float* ln2_b  = (const float*)d_in[7];
  const float* fc1_w  = (const float*)d_in[8];
  const float* fc1_b  = (const float*)d_in[9];
  const float* fc2_w  = (const float*)d_in[10];
  const float* fc2_b  = (const float*)d_in[11];

  char* ws = (char*)d_ws;
  u16t* h1   = (u16t*)(ws + 0);           // 8192x768 bf16 (ln1 out; REUSED as vt; then ln2 out)
  u16t* qkvb = (u16t*)(ws + 12582912);    // 8192x2304 bf16
  u16t* ctx  = (u16t*)(ws + 50331648);    // 8192x768 bf16
  float* x2  = (float*)(ws + 62914560);   // 8192x768 f32
  u16t* hid  = (u16t*)(ws + 88080384);    // 8192x3072 bf16
  u16t* wq   = (u16t*)(ws + 138412032);   // 2304x768 bf16
  u16t* wp   = (u16t*)(ws + 141950976);   // 768x768 bf16
  u16t* w1   = (u16t*)(ws + 143130624);   // 3072x768 bf16
  u16t* w2   = (u16t*)(ws + 147849216);   // 768x3072 bf16
  u16t* vtb  = h1;                        // 96x64x1024 bf16, lifetime-disjoint
  float* out = (float*)d_out;

  cvt_all_kernel<<<3456, 256, 0, stream>>>(qkv_w, proj_w, fc1_w, fc2_w, wq, wp, w1, w2);

  ln_kernel<<<8192, 256, 0, stream>>>(x, ln1_g, ln1_b, h1);
  // qkv: grid 18*64 = 1152 (div by 8)
  gemm_bt<0><<<1152, 256, 0, stream>>>(h1, wq, qkvb, nullptr, nullptr, 2304, 768);
  vtrans_kernel<<<dim3(96, 16), 256, 0, stream>>>(qkvb, vtb);
  attn_kernel<<<768, 256, 0, stream>>>(qkvb, vtb, ctx);
  // proj: grid 6*64 = 384
  gemm_bt<1><<<384, 256, 0, stream>>>(ctx, wp, x2, proj_b, x, 768, 768);
  ln_kernel<<<8192, 256, 0, stream>>>(x2, ln2_g, ln2_b, h1);
  // fc1: grid 24*64 = 1536
  gemm_bt<2><<<1536, 256, 0, stream>>>(h1, w1, hid, fc1_b, nullptr, 3072, 768);
  // fc2: grid 6*64 = 384, K=3072
  gemm_bt<1><<<384, 256, 0, stream>>>(hid, w2, out, fc2_b, x2, 768, 3072);
}